// Round 19
// baseline (6227.412 us; speedup 1.0000x reference)
//
#include <hip/hip_runtime.h>

#define HW 147456  // 384*384

typedef __attribute__((ext_vector_type(8))) short bf16x8;
typedef __attribute__((ext_vector_type(4))) float f32x4;

__device__ __forceinline__ float bf2f(unsigned short u) {
    return __uint_as_float(((unsigned)u) << 16);
}
__device__ __forceinline__ unsigned short f2bf(float f) {
    unsigned u = __float_as_uint(f);
    return (unsigned short)((u + 0x7fffu + ((u >> 16) & 1u)) >> 16);  // RNE
}

// ---------------- fp32 weight transpose: w[COUT][CINTOT][K] -> wT[cin][k][COUTP] ----------------
struct TJobs {
    const float* src[5];
    float* dst[5];
    int cout[5], cintot[5], k[5], coutp[5];
    int start[6];
};

__global__ __launch_bounds__(256) void transpose_all_k(TJobs J) {
    int gid = blockIdx.x * 256 + threadIdx.x;
    if (gid >= J.start[5]) return;
    int j = 0;
#pragma unroll
    for (int t = 1; t < 5; ++t)
        if (gid >= J.start[t]) j = t;
    int li = gid - J.start[j];
    int coutp = J.coutp[j], K = J.k[j];
    int co = li % coutp;
    int kk = (li / coutp) % K;
    int cin = li / (coutp * K);
    J.dst[j][li] = (co < J.cout[j]) ? J.src[j][((co * J.cintot[j]) + cin) * K + kk] : 0.f;
}

// ---------------- bf16 weight prep for MFMA: w[COUT][CINTOT][9] -> wB[9][COUT][CINP] ----------------
struct WJobs {
    const float* src[4];
    unsigned short* dst[4];
    int cout[4], cin[4], cintot[4], cinp[4];
    int start[5];
};

__global__ __launch_bounds__(256) void transpose_wbf_k(WJobs J) {
    int gid = blockIdx.x * 256 + threadIdx.x;
    if (gid >= J.start[4]) return;
    int j = 0;
#pragma unroll
    for (int t = 1; t < 4; ++t)
        if (gid >= J.start[t]) j = t;
    int li = gid - J.start[j];
    int cinp = J.cinp[j];
    int ci = li % cinp;
    int co = (li / cinp) % J.cout[j];
    int tap = li / (cinp * J.cout[j]);
    float v = (ci < J.cin[j]) ? J.src[j][((co * J.cintot[j]) + ci) * 9 + tap] : 0.f;
    J.dst[j][li] = f2bf(v);
}

// ---------------- bf16 MFMA implicit-GEMM 3x3 conv, pad=1, optional ReLU ----------------
template <int CIN, int CP, int COUT, int S, int OX, int OY, int MW, bool RELU>
__global__ __launch_bounds__(256, MW) void mfma_conv_k(
    const float* __restrict__ in0, const float* __restrict__ in1, int split,
    long off0base, long off1base, long zs0, long zs1, int inW, int inH,
    const unsigned short* __restrict__ wB,  // [9][COUT][CINK] bf16
    const float* __restrict__ bias,
    float* __restrict__ out, long outZS) {
    constexpr int XT = (OX - 1) * S + 3;
    constexpr int YT = (OY - 1) * S + 3;
    constexpr int CINK = (CIN + 31) & ~31;
    constexpr int KST = CINK / 32;
    constexpr int NCG = COUT / 16;
    constexpr int NTX = OX / 16;
    constexpr int NSP = NTX * OY;
    constexpr int NTASK = NSP * NCG;
    constexpr int NT4 = NTASK / 4;
    constexpr int NSLOT = YT * XT;
    static_assert(NTASK % 4 == 0, "tasks per wave");
    static_assert(NSP % NT4 == 0, "wave must own a single cout-group");
    static_assert(CP % 8 == 0 && CP >= CINK, "LDS cin pad");
    static_assert((CP / 8) % 2 == 1, "odd chunk stride for bank spread");
    __shared__ __align__(16) unsigned short tile[NSLOT * CP];
    const int tid = threadIdx.x;
    const int bx = blockIdx.x, by = blockIdx.y, z = blockIdx.z;
    const long o0 = off0base + (long)z * zs0;
    const long o1 = off1base + (long)z * zs1;
    const int outW = inW / S, outH = inH / S;
    const int gx0 = bx * OX * S - 1;
    const int gy0 = by * OY * S - 1;

#pragma unroll 1
    for (int s = tid; s < NSLOT; s += 256) {
        const int sy = s / XT;
        const int lx = s - sy * XT;
        const int gy = gy0 + sy;
        const int gx = gx0 + lx;
        const bool ok = ((unsigned)gy < (unsigned)inH) && ((unsigned)gx < (unsigned)inW);
        const long pix = (long)gy * inW + gx;
#pragma unroll
        for (int h = 0; h < CINK / 8; ++h) {
            bf16x8 v;
#pragma unroll
            for (int e = 0; e < 8; ++e) {
                const int c = h * 8 + e;
                float f = 0.f;
                if (c < CIN && ok) {
                    const float* base = (c < split)
                        ? in0 + o0 + (long)c * inH * inW
                        : in1 + o1 + (long)(c - split) * inH * inW;
                    f = base[pix];
                }
                v[e] = (short)f2bf(f);
            }
            *(bf16x8*)(tile + s * CP + h * 8) = v;
        }
    }
    __syncthreads();

    const int wv = tid >> 6;
    const int l = tid & 63;
    const int ln = l & 15;
    const int lk = l >> 4;
    const int cg = (wv * NT4) / NSP;
    bf16x8 bfr[9 * KST];
#pragma unroll
    for (int tap = 0; tap < 9; ++tap)
#pragma unroll
        for (int h = 0; h < KST; ++h)
            bfr[tap * KST + h] = *(const bf16x8*)(wB + ((long)(tap * COUT + cg * 16 + ln)) * CINK + h * 32 + lk * 8);
    const float bv = bias[cg * 16 + ln];
#pragma unroll 1
    for (int t = 0; t < NT4; ++t) {
        const int sp = wv * NT4 + t - cg * NSP;
        const int tx = sp % NTX;
        const int ty = sp / NTX;
        f32x4 acc;
        acc[0] = bv; acc[1] = bv; acc[2] = bv; acc[3] = bv;
#pragma unroll
        for (int ky = 0; ky < 3; ++ky) {
#pragma unroll
            for (int kx = 0; kx < 3; ++kx) {
                const int yb = ty * S + ky;
                const int xb = (tx * 16 + ln) * S + kx;
                const unsigned short* ap = tile + (yb * XT + xb) * CP + lk * 8;
#pragma unroll
                for (int h = 0; h < KST; ++h) {
                    bf16x8 a = *(const bf16x8*)(ap + h * 32);
                    acc = __builtin_amdgcn_mfma_f32_16x16x32_bf16(a, bfr[(ky * 3 + kx) * KST + h], acc, 0, 0, 0);
                }
            }
        }
        const int ox = bx * OX + tx * 16 + lk * 4;
        const int oy = by * OY + ty;
        float4 o;
        if constexpr (RELU) {
            o.x = fmaxf(acc[0], 0.f);
            o.y = fmaxf(acc[1], 0.f);
            o.z = fmaxf(acc[2], 0.f);
            o.w = fmaxf(acc[3], 0.f);
        } else {
            o.x = acc[0]; o.y = acc[1]; o.z = acc[2]; o.w = acc[3];
        }
        *(float4*)(out + (long)z * outZS + ((long)(cg * 16 + ln) * outH + oy) * outW + ox) = o;
    }
}

// ---------------- fp32 LDS-tiled 3x3 conv (stem only: precision-critical) ----------------
template <int CIN, int CCHUNK, int WCH, int COUT, int STRIDE, int TW, int CO_PER, int MW>
__global__ __launch_bounds__(256, MW) void conv3x3_k(
    const float* __restrict__ in0, const float* __restrict__ in1, int split,
    long inOff0, long inOff1, long zs0, long zs1, int inW, int inH,
    const float* __restrict__ wT, const float* __restrict__ bias,
    float* __restrict__ out, long outZS) {
    constexpr int NCG = COUT / CO_PER;
    constexpr int NPXG = 256 / NCG;
    constexpr int NXG = TW / 4;
    constexpr int TH = NPXG / NXG;
    constexpr int INW = (TW - 1) * STRIDE + 3;
    constexpr int INH = (TH - 1) * STRIDE + 3;
    constexpr int WIN = 3 * STRIDE + 3;
    constexpr int XV = (INW + 6) / 4;
    constexpr int LDSW = XV * 4 + 1;
    constexpr int SLOTS = INH * XV;
    static_assert(NPXG % NXG == 0 && NPXG * NCG == 256, "thread mapping");
    static_assert(CIN % CCHUNK == 0 && CCHUNK % WCH == 0, "chunking");
    static_assert(SLOTS <= 256, "staging slots");
    __shared__ float tile[CCHUNK][INH][LDSW];
    __shared__ __align__(16) float wlds[WCH * 9 * COUT];
    const int tid = threadIdx.x;
    const int cg = tid / NPXG;
    const int pg = tid % NPXG;
    const int xg = pg % NXG;
    const int yy = pg / NXG;
    const int bx = blockIdx.x, by = blockIdx.y, z = blockIdx.z;
    const int outW = inW / STRIDE, outH = inH / STRIDE;
    const long off0 = inOff0 + (long)z * zs0;
    const long off1 = inOff1 + (long)z * zs1;
    float* outp = out + (long)z * outZS;
    const bool sact = tid < SLOTS;
    const int sr = tid / XV;
    const int sx = tid - sr * XV;
    const int gxs = bx * TW * STRIDE - 4 + sx * 4;
    const int gy0 = by * TH * STRIDE - 1;

    float acc[4][CO_PER];
    {
        float bv[CO_PER];
#pragma unroll
        for (int jj = 0; jj < CO_PER; jj += 4) {
            float4 b4 = *(const float4*)(bias + cg * CO_PER + jj);
            bv[jj] = b4.x; bv[jj + 1] = b4.y; bv[jj + 2] = b4.z; bv[jj + 3] = b4.w;
        }
#pragma unroll
        for (int p = 0; p < 4; ++p)
#pragma unroll
            for (int j = 0; j < CO_PER; ++j) acc[p][j] = bv[j];
    }

    for (int ch = 0; ch < CIN; ch += CCHUNK) {
        if (sact) {
            const int gy = gy0 + sr;
            const bool yok = (unsigned)gy < (unsigned)inH;
            const bool xfull = (gxs >= 0) && (gxs + 3 < inW);
#pragma unroll
            for (int c = 0; c < CCHUNK; ++c) {
                const int gc = ch + c;
                const float* row = (gc < split)
                    ? in0 + off0 + ((long)gc * inH + gy) * inW
                    : in1 + off1 + ((long)(gc - split) * inH + gy) * inW;
                float4 v = {0.f, 0.f, 0.f, 0.f};
                if (yok) {
                    if (xfull) {
                        v = *(const float4*)(row + gxs);
                    } else {
                        float t[4];
#pragma unroll
                        for (int k = 0; k < 4; ++k) {
                            int gx = gxs + k;
                            t[k] = ((unsigned)gx < (unsigned)inW) ? row[gx] : 0.f;
                        }
                        v = {t[0], t[1], t[2], t[3]};
                    }
                }
                float* dst = &tile[c][sr][sx * 4];
                dst[0] = v.x; dst[1] = v.y; dst[2] = v.z; dst[3] = v.w;
            }
        }
#pragma unroll 1
        for (int wc = 0; wc < CCHUNK; wc += WCH) {
            {
                const float4* wsrc = (const float4*)(wT + (long)(ch + wc) * 9 * COUT);
                float4* wdst = (float4*)wlds;
                constexpr int CNT = WCH * 9 * COUT / 4;
                for (int i = tid; i < CNT; i += 256) wdst[i] = wsrc[i];
            }
            __syncthreads();
#pragma unroll 1
            for (int c = 0; c < WCH; ++c) {
#pragma unroll
                for (int ky = 0; ky < 3; ++ky) {
                    const int ty = yy * STRIDE + ky;
                    const int tx0 = xg * 4 * STRIDE + 3;
                    float xw[WIN];
#pragma unroll
                    for (int i = 0; i < WIN; ++i) xw[i] = tile[wc + c][ty][tx0 + i];
#pragma unroll
                    for (int dx = 0; dx < 3; ++dx) {
                        const float* wp = wlds + ((c * 3 + ky) * 3 + dx) * COUT + cg * CO_PER;
                        float wv[CO_PER];
#pragma unroll
                        for (int jj = 0; jj < CO_PER; jj += 4) {
                            float4 w4 = *(const float4*)(wp + jj);
                            wv[jj] = w4.x; wv[jj + 1] = w4.y; wv[jj + 2] = w4.z; wv[jj + 3] = w4.w;
                        }
#pragma unroll
                        for (int p = 0; p < 4; ++p) {
                            float xv = xw[p * STRIDE + dx];
#pragma unroll
                            for (int j = 0; j < CO_PER; ++j) acc[p][j] = fmaf(xv, wv[j], acc[p][j]);
                        }
                    }
                }
            }
            __syncthreads();
        }
    }

    const int ox0 = bx * TW + xg * 4;
    const int oy = by * TH + yy;
#pragma unroll
    for (int j = 0; j < CO_PER; ++j) {
        int co = cg * CO_PER + j;
        float4 o;
        o.x = fmaxf(acc[0][j], 0.f);
        o.y = fmaxf(acc[1][j], 0.f);
        o.z = fmaxf(acc[2][j], 0.f);
        o.w = fmaxf(acc[3][j], 0.f);
        *(float4*)(outp + ((long)co * outH + oy) * outW + ox0) = o;
    }
}

// ---------------- spatial mean over 96x96 plane, z-batched ----------------
__global__ __launch_bounds__(256) void pool_k(const float* __restrict__ enc3base,
                                              long zstride,
                                              float* __restrict__ meanout) {
    int z = blockIdx.x >> 6;
    int c = blockIdx.x & 63;
    const float* p = enc3base + (long)z * zstride + (long)c * 9216;
    float s = 0.f;
    for (int i = threadIdx.x; i < 9216; i += 256) s += p[i];
    __shared__ float red[256];
    red[threadIdx.x] = s;
    __syncthreads();
    for (int o = 128; o > 0; o >>= 1) {
        if (threadIdx.x < o) red[threadIdx.x] += red[threadIdx.x + o];
        __syncthreads();
    }
    if (threadIdx.x == 0) meanout[z * 64 + c] = red[0] * (1.f / 9216.f);
}

// ---------------- task embedding + te-derived constants ----------------
__global__ __launch_bounds__(256) void prep_te_k(
    const float* __restrict__ means, const float* __restrict__ lw,
    const float* __restrict__ lb, const float* __restrict__ tauw,
    const float* __restrict__ taub, const float* __restrict__ w1,
    const float* __restrict__ b1,
    float* __restrict__ tauc, float* __restrict__ wsum,
    float* __restrict__ bias2) {
    __shared__ float tes[64];
    int t = threadIdx.x;
    if (t < 64) {
        float s = 0.f;
        for (int d = 0; d < 4; ++d)
            for (int c = 0; c < 64; ++c) s += means[d * 64 + c] * lw[t * 64 + c];
        tes[t] = lb[t] + 0.25f * s;
    }
    __syncthreads();
    if (t < 32) {
        float s = taub[t];
        for (int e = 0; e < 64; ++e) s += tauw[t * 96 + 32 + e] * tes[e];
        tauc[t] = s;
    }
    for (int i = t; i < 288; i += 256) {
        int co = i % 32;
        int k = i / 32;
        float s = 0.f;
        for (int e = 0; e < 64; ++e) s += w1[((co * 96) + 32 + e) * 9 + k] * tes[e];
        wsum[i] = s;
    }
    __syncthreads();
    if (t < 32) {
        float s = b1[t];
        for (int k = 0; k < 9; ++k) s += wsum[k * 32 + t];
        bias2[t] = s;  // b1 + full 9-tap te sum (border fixed in nca_fuse_k)
    }
}

// ---------------- fused NCA 1x1s + gate (reads h1_raw, writes s_new IN PLACE) ----------------
// 1 px/thread, all 32 couts; ci loop FULLY unrolled so sarr/accd/acct are
// statically indexed -> registers (R18's partial unroll put sarr in scratch:
// 196 MB WRITE_SIZE, 97us). h1 = relu(h1_raw - border_corr).
__global__ __launch_bounds__(256, 2) void nca_fuse_k(
    const float* __restrict__ sold, float* __restrict__ hb,  // h1_raw in, s_new out
    const float* __restrict__ wsum, const float* __restrict__ w2T,
    const float* __restrict__ b2, const float* __restrict__ tauT,
    const float* __restrict__ tauc) {
    __shared__ float sw2[1024], stu[1024], swv[288], sb2[32], stc[32];
    const int tid = threadIdx.x;
    for (int i = tid; i < 1024; i += 256) {
        sw2[i] = w2T[i];
        stu[i] = tauT[i];
    }
    for (int i = tid; i < 288; i += 256) swv[i] = wsum[i];
    if (tid < 32) {
        sb2[tid] = b2[tid];
        stc[tid] = tauc[tid];
    }
    __syncthreads();
    const long px = (long)blockIdx.x * 256 + tid;
    const int y = (int)(px / 384);
    const int x = (int)(px - (long)y * 384);
    unsigned mask = 0;
#pragma unroll
    for (int ky = 0; ky < 3; ++ky)
#pragma unroll
        for (int kx = 0; kx < 3; ++kx) {
            int yy = y - 1 + ky, xx = x - 1 + kx;
            if ((unsigned)yy < 384u && (unsigned)xx < 384u) mask |= 1u << (ky * 3 + kx);
        }
    const bool interior = (mask == 0x1FFu);

    float sarr[32], accd[32], acct[32];
#pragma unroll
    for (int co = 0; co < 32; ++co) {
        accd[co] = sb2[co];
        acct[co] = stc[co];
    }
#pragma unroll
    for (int ci = 0; ci < 32; ++ci) {  // FULL unroll: static indices everywhere
        float h = hb[(long)ci * HW + px];
        float sv = sold[(long)ci * HW + px];
        sarr[ci] = sv;
        if (!interior) {
#pragma unroll
            for (int t = 0; t < 9; ++t)
                if (!((mask >> t) & 1u)) h -= swv[t * 32 + ci];
        }
        h = fmaxf(h, 0.f);
        const float* wd = sw2 + ci * 32;
        const float* wt = stu + ci * 32;
#pragma unroll
        for (int co = 0; co < 32; ++co) {
            accd[co] = fmaf(h, wd[co], accd[co]);
            acct[co] = fmaf(sv, wt[co], acct[co]);
        }
    }
#pragma unroll
    for (int co = 0; co < 32; ++co) {
        float beta = 1.f / (1.f + __expf(-acct[co]));
        hb[(long)co * HW + px] = beta * sarr[co] + (1.f - beta) * accd[co];
    }
}

// ---------------- decode 1x1 -> fp32 output ----------------
__global__ __launch_bounds__(256) void dec_k(const float* __restrict__ st,
                                             const float* __restrict__ dT,
                                             const float* __restrict__ db,
                                             float* __restrict__ out) {
    int gid = blockIdx.x * 256 + threadIdx.x;
    long px0 = (long)gid * 2;
    float acc[11][2];
#pragma unroll
    for (int co = 0; co < 11; ++co) {
        float b = db[co];
        acc[co][0] = b;
        acc[co][1] = b;
    }
    for (int ci = 0; ci < 32; ++ci) {
        float2 s2 = *(const float2*)(st + (long)ci * HW + px0);
        const float* wp = dT + ci * 12;
        float4 w0 = *(const float4*)wp, w1 = *(const float4*)(wp + 4), w2 = *(const float4*)(wp + 8);
        float wv[12] = {w0.x, w0.y, w0.z, w0.w, w1.x, w1.y, w1.z, w1.w, w2.x, w2.y, w2.z, w2.w};
#pragma unroll
        for (int co = 0; co < 11; ++co) {
            acc[co][0] = fmaf(s2.x, wv[co], acc[co][0]);
            acc[co][1] = fmaf(s2.y, wv[co], acc[co][1]);
        }
    }
#pragma unroll
    for (int co = 0; co < 11; ++co) {
        float2 o = {acc[co][0], acc[co][1]};
        *(float2*)(out + (long)co * HW + px0) = o;
    }
}

extern "C" void kernel_launch(void* const* d_in, const int* in_sizes, int n_in,
                              void* d_out, int out_size, void* d_ws, size_t ws_size,
                              hipStream_t stream) {
    float* out = (float*)d_out;
    const float* demo_in = (const float*)d_in[0];
    const float* demo_out = (const float*)d_in[1];
    const float* test_in = (const float*)d_in[2];
    const float* enc_w1 = (const float*)d_in[3];
    const float* enc_b1 = (const float*)d_in[4];
    const float* enc_w2 = (const float*)d_in[5];
    const float* enc_b2 = (const float*)d_in[6];
    const float* enc_w3 = (const float*)d_in[7];
    const float* enc_b3 = (const float*)d_in[8];
    const float* enc_lw = (const float*)d_in[9];
    const float* enc_lb = (const float*)d_in[10];
    const float* stem_w = (const float*)d_in[11];
    const float* stem_b = (const float*)d_in[12];
    const float* upd_w1 = (const float*)d_in[13];
    const float* upd_b1 = (const float*)d_in[14];
    const float* upd_w2 = (const float*)d_in[15];
    const float* upd_b2 = (const float*)d_in[16];
    const float* tau_w = (const float*)d_in[17];
    const float* tau_b = (const float*)d_in[18];
    const float* dec_w = (const float*)d_in[19];
    const float* dec_b = (const float*)d_in[20];

    // ---- workspace layout (floats) ----
    float* Wb = (float*)d_ws;
    float* wT_D = Wb + 0;        // 3744 (stem fp32)
    float* w2T  = Wb + 3744;     // 1024
    float* tauT = Wb + 4768;     // 1024
    float* decT = Wb + 5792;     // 384
    float* tauc = Wb + 6176;     // 32
    float* wsum = Wb + 6208;     // 288
    float* means = Wb + 6496;    // 256
    float* bias2 = Wb + 6752;    // 32
    unsigned short* wB1 = (unsigned short*)(Wb + 6784);   // 9*32*32 bf16 (4608 f)
    unsigned short* wB2 = (unsigned short*)(Wb + 11392);  // 9*64*32 (9216 f)
    unsigned short* wB3 = (unsigned short*)(Wb + 20608);  // 9*64*64 (18432 f)
    unsigned short* wBE = (unsigned short*)(Wb + 39040);  // 9*32*32 (4608 f)
    float* big = Wb + 45056;

    const long PD = 7667712;  // per-demo floats (enc1+enc2+enc3)
    const long E1 = 4718592, E2 = 2359296;
    size_t wsf = ws_size / 4;
    int NZ = 1;
    if (wsf >= 45056 + 4 * (size_t)PD) NZ = 4;
    else if (wsf >= 45056 + 2 * (size_t)PD) NZ = 2;

    // ---- fp32 weight transposes (stem + 1x1s + dec) ----
    TJobs J;
    {
        const float* srcs[5] = {stem_w, upd_w2, tau_w, dec_w, dec_w};
        float* dsts[5] = {wT_D, w2T, tauT, decT, decT};
        int couts[5] = {32, 32, 32, 11, 0};
        int cintots[5] = {13, 32, 96, 32, 32};
        int ks[5] = {9, 1, 1, 1, 1};
        int cinsels[5] = {13, 32, 32, 32, 0};
        int coutps[5] = {32, 32, 32, 12, 12};
        int acc0 = 0;
        for (int j = 0; j < 5; ++j) {
            J.src[j] = srcs[j]; J.dst[j] = dsts[j];
            J.cout[j] = couts[j]; J.cintot[j] = cintots[j];
            J.k[j] = ks[j]; J.coutp[j] = coutps[j];
            J.start[j] = acc0;
            acc0 += cinsels[j] * ks[j] * coutps[j];
        }
        J.start[5] = acc0;
        transpose_all_k<<<(acc0 + 255) / 256, 256, 0, stream>>>(J);
    }
    // ---- bf16 MFMA weights (encoder convs + nca 3x3 state part) ----
    WJobs W;
    {
        const float* srcs[4] = {enc_w1, enc_w2, enc_w3, upd_w1};
        unsigned short* dsts[4] = {wB1, wB2, wB3, wBE};
        int couts[4] = {32, 64, 64, 32};
        int cins[4] = {26, 32, 64, 32};
        int cintots[4] = {26, 32, 64, 96};
        int cinps[4] = {32, 32, 64, 32};
        int acc0 = 0;
        for (int j = 0; j < 4; ++j) {
            W.src[j] = srcs[j]; W.dst[j] = dsts[j];
            W.cout[j] = couts[j]; W.cin[j] = cins[j];
            W.cintot[j] = cintots[j]; W.cinp[j] = cinps[j];
            W.start[j] = acc0;
            acc0 += 9 * couts[j] * cinps[j];
        }
        W.start[4] = acc0;
        transpose_wbf_k<<<(acc0 + 255) / 256, 256, 0, stream>>>(W);
    }

    // ---- encoder (bf16 MFMA), NZ demos per launch ----
    for (int d0 = 0; d0 < 4; d0 += NZ) {
        mfma_conv_k<26, 40, 32, 1, 64, 4, 5, true><<<dim3(6, 96, NZ), 256, 0, stream>>>(
            demo_in, demo_out, 13, (long)d0 * 13 * HW, (long)d0 * 13 * HW,
            13L * HW, 13L * HW, 384, 384, wB1, enc_b1, big, PD);
        mfma_conv_k<32, 40, 64, 2, 32, 2, 5, true><<<dim3(6, 96, NZ), 256, 0, stream>>>(
            big, big, 32, 0, 0, PD, PD, 384, 384, wB2, enc_b2, big + E1, PD);
        mfma_conv_k<64, 72, 64, 2, 16, 2, 5, true><<<dim3(6, 48, NZ), 256, 0, stream>>>(
            big + E1, big + E1, 64, 0, 0, PD, PD, 192, 192, wB3, enc_b3,
            big + E1 + E2, PD);
        pool_k<<<64 * NZ, 256, 0, stream>>>(big + E1 + E2, PD, means + d0 * 64);
    }
    prep_te_k<<<1, 256, 0, stream>>>(means, enc_lw, enc_lb, tau_w, tau_b, upd_w1,
                                     upd_b1, tauc, wsum, bias2);

    // ---- stem (fp32 exact) -> sA ----
    float* sA = big;
    float* sX = big + E1;
    conv3x3_k<13, 13, 13, 32, 1, 32, 8, 5><<<dim3(12, 48, 1), 256, 0, stream>>>(
        test_in, test_in, 13, 0, 0, 0, 0, 384, 384, wT_D, stem_b, sA, 0);

    // ---- 8 NCA steps: A) mfma 3x3 -> h1_raw(b)   B) fused 1x1s+gate (b in place)
    float* a = sA;
    float* b = sX;
    for (int s = 0; s < 8; ++s) {
        mfma_conv_k<32, 40, 32, 1, 32, 8, 5, false><<<dim3(12, 48, 1), 256, 0, stream>>>(
            a, a, 32, 0, 0, 0, 0, 384, 384, wBE, bias2, b, 0);
        nca_fuse_k<<<576, 256, 0, stream>>>(a, b, wsum, w2T, upd_b2, tauT, tauc);
        float* t = a; a = b; b = t;
    }
    dec_k<<<288, 256, 0, stream>>>(a, decT, dec_b, out);
}

// Round 20
// 4121.772 us; speedup vs baseline: 1.5109x; 1.5109x over previous
//
#include <hip/hip_runtime.h>

#define HW 147456  // 384*384

typedef __attribute__((ext_vector_type(8))) short bf16x8;
typedef __attribute__((ext_vector_type(4))) float f32x4;

__device__ __forceinline__ float bf2f(unsigned short u) {
    return __uint_as_float(((unsigned)u) << 16);
}
__device__ __forceinline__ unsigned short f2bf(float f) {
    unsigned u = __float_as_uint(f);
    return (unsigned short)((u + 0x7fffu + ((u >> 16) & 1u)) >> 16);  // RNE
}

// ---------------- fp32 weight transpose: w[COUT][CINTOT][K] -> wT[cin][k][COUTP] ----------------
struct TJobs {
    const float* src[5];
    float* dst[5];
    int cout[5], cintot[5], k[5], coutp[5];
    int start[6];
};

__global__ __launch_bounds__(256) void transpose_all_k(TJobs J) {
    int gid = blockIdx.x * 256 + threadIdx.x;
    if (gid >= J.start[5]) return;
    int j = 0;
#pragma unroll
    for (int t = 1; t < 5; ++t)
        if (gid >= J.start[t]) j = t;
    int li = gid - J.start[j];
    int coutp = J.coutp[j], K = J.k[j];
    int co = li % coutp;
    int kk = (li / coutp) % K;
    int cin = li / (coutp * K);
    J.dst[j][li] = (co < J.cout[j]) ? J.src[j][((co * J.cintot[j]) + cin) * K + kk] : 0.f;
}

// ---------------- bf16 weight prep for MFMA: w[COUT][CINTOT][9] -> wB[9][COUT][CINP] ----------------
struct WJobs {
    const float* src[4];
    unsigned short* dst[4];
    int cout[4], cin[4], cintot[4], cinp[4];
    int start[5];
};

__global__ __launch_bounds__(256) void transpose_wbf_k(WJobs J) {
    int gid = blockIdx.x * 256 + threadIdx.x;
    if (gid >= J.start[4]) return;
    int j = 0;
#pragma unroll
    for (int t = 1; t < 4; ++t)
        if (gid >= J.start[t]) j = t;
    int li = gid - J.start[j];
    int cinp = J.cinp[j];
    int ci = li % cinp;
    int co = (li / cinp) % J.cout[j];
    int tap = li / (cinp * J.cout[j]);
    float v = (ci < J.cin[j]) ? J.src[j][((co * J.cintot[j]) + ci) * 9 + tap] : 0.f;
    J.dst[j][li] = f2bf(v);
}

// ---------------- bf16 MFMA implicit-GEMM 3x3 conv, pad=1, optional ReLU ----------------
template <int CIN, int CP, int COUT, int S, int OX, int OY, int MW, bool RELU>
__global__ __launch_bounds__(256, MW) void mfma_conv_k(
    const float* __restrict__ in0, const float* __restrict__ in1, int split,
    long off0base, long off1base, long zs0, long zs1, int inW, int inH,
    const unsigned short* __restrict__ wB,  // [9][COUT][CINK] bf16
    const float* __restrict__ bias,
    float* __restrict__ out, long outZS) {
    constexpr int XT = (OX - 1) * S + 3;
    constexpr int YT = (OY - 1) * S + 3;
    constexpr int CINK = (CIN + 31) & ~31;
    constexpr int KST = CINK / 32;
    constexpr int NCG = COUT / 16;
    constexpr int NTX = OX / 16;
    constexpr int NSP = NTX * OY;
    constexpr int NTASK = NSP * NCG;
    constexpr int NT4 = NTASK / 4;
    constexpr int NSLOT = YT * XT;
    static_assert(NTASK % 4 == 0, "tasks per wave");
    static_assert(NSP % NT4 == 0, "wave must own a single cout-group");
    static_assert(CP % 8 == 0 && CP >= CINK, "LDS cin pad");
    static_assert((CP / 8) % 2 == 1, "odd chunk stride for bank spread");
    __shared__ __align__(16) unsigned short tile[NSLOT * CP];
    const int tid = threadIdx.x;
    const int bx = blockIdx.x, by = blockIdx.y, z = blockIdx.z;
    const long o0 = off0base + (long)z * zs0;
    const long o1 = off1base + (long)z * zs1;
    const int outW = inW / S, outH = inH / S;
    const int gx0 = bx * OX * S - 1;
    const int gy0 = by * OY * S - 1;

#pragma unroll 1
    for (int s = tid; s < NSLOT; s += 256) {
        const int sy = s / XT;
        const int lx = s - sy * XT;
        const int gy = gy0 + sy;
        const int gx = gx0 + lx;
        const bool ok = ((unsigned)gy < (unsigned)inH) && ((unsigned)gx < (unsigned)inW);
        const long pix = (long)gy * inW + gx;
#pragma unroll
        for (int h = 0; h < CINK / 8; ++h) {
            bf16x8 v;
#pragma unroll
            for (int e = 0; e < 8; ++e) {
                const int c = h * 8 + e;
                float f = 0.f;
                if (c < CIN && ok) {
                    const float* base = (c < split)
                        ? in0 + o0 + (long)c * inH * inW
                        : in1 + o1 + (long)(c - split) * inH * inW;
                    f = base[pix];
                }
                v[e] = (short)f2bf(f);
            }
            *(bf16x8*)(tile + s * CP + h * 8) = v;
        }
    }
    __syncthreads();

    const int wv = tid >> 6;
    const int l = tid & 63;
    const int ln = l & 15;
    const int lk = l >> 4;
    const int cg = (wv * NT4) / NSP;
    bf16x8 bfr[9 * KST];
#pragma unroll
    for (int tap = 0; tap < 9; ++tap)
#pragma unroll
        for (int h = 0; h < KST; ++h)
            bfr[tap * KST + h] = *(const bf16x8*)(wB + ((long)(tap * COUT + cg * 16 + ln)) * CINK + h * 32 + lk * 8);
    const float bv = bias[cg * 16 + ln];
#pragma unroll 1
    for (int t = 0; t < NT4; ++t) {
        const int sp = wv * NT4 + t - cg * NSP;
        const int tx = sp % NTX;
        const int ty = sp / NTX;
        f32x4 acc;
        acc[0] = bv; acc[1] = bv; acc[2] = bv; acc[3] = bv;
#pragma unroll
        for (int ky = 0; ky < 3; ++ky) {
#pragma unroll
            for (int kx = 0; kx < 3; ++kx) {
                const int yb = ty * S + ky;
                const int xb = (tx * 16 + ln) * S + kx;
                const unsigned short* ap = tile + (yb * XT + xb) * CP + lk * 8;
#pragma unroll
                for (int h = 0; h < KST; ++h) {
                    bf16x8 a = *(const bf16x8*)(ap + h * 32);
                    acc = __builtin_amdgcn_mfma_f32_16x16x32_bf16(a, bfr[(ky * 3 + kx) * KST + h], acc, 0, 0, 0);
                }
            }
        }
        const int ox = bx * OX + tx * 16 + lk * 4;
        const int oy = by * OY + ty;
        float4 o;
        if constexpr (RELU) {
            o.x = fmaxf(acc[0], 0.f);
            o.y = fmaxf(acc[1], 0.f);
            o.z = fmaxf(acc[2], 0.f);
            o.w = fmaxf(acc[3], 0.f);
        } else {
            o.x = acc[0]; o.y = acc[1]; o.z = acc[2]; o.w = acc[3];
        }
        *(float4*)(out + (long)z * outZS + ((long)(cg * 16 + ln) * outH + oy) * outW + ox) = o;
    }
}

// ---------------- fp32 LDS-tiled 3x3 conv (stem only: precision-critical) ----------------
template <int CIN, int CCHUNK, int WCH, int COUT, int STRIDE, int TW, int CO_PER, int MW>
__global__ __launch_bounds__(256, MW) void conv3x3_k(
    const float* __restrict__ in0, const float* __restrict__ in1, int split,
    long inOff0, long inOff1, long zs0, long zs1, int inW, int inH,
    const float* __restrict__ wT, const float* __restrict__ bias,
    float* __restrict__ out, long outZS) {
    constexpr int NCG = COUT / CO_PER;
    constexpr int NPXG = 256 / NCG;
    constexpr int NXG = TW / 4;
    constexpr int TH = NPXG / NXG;
    constexpr int INW = (TW - 1) * STRIDE + 3;
    constexpr int INH = (TH - 1) * STRIDE + 3;
    constexpr int WIN = 3 * STRIDE + 3;
    constexpr int XV = (INW + 6) / 4;
    constexpr int LDSW = XV * 4 + 1;
    constexpr int SLOTS = INH * XV;
    static_assert(NPXG % NXG == 0 && NPXG * NCG == 256, "thread mapping");
    static_assert(CIN % CCHUNK == 0 && CCHUNK % WCH == 0, "chunking");
    static_assert(SLOTS <= 256, "staging slots");
    __shared__ float tile[CCHUNK][INH][LDSW];
    __shared__ __align__(16) float wlds[WCH * 9 * COUT];
    const int tid = threadIdx.x;
    const int cg = tid / NPXG;
    const int pg = tid % NPXG;
    const int xg = pg % NXG;
    const int yy = pg / NXG;
    const int bx = blockIdx.x, by = blockIdx.y, z = blockIdx.z;
    const int outW = inW / STRIDE, outH = inH / STRIDE;
    const long off0 = inOff0 + (long)z * zs0;
    const long off1 = inOff1 + (long)z * zs1;
    float* outp = out + (long)z * outZS;
    const bool sact = tid < SLOTS;
    const int sr = tid / XV;
    const int sx = tid - sr * XV;
    const int gxs = bx * TW * STRIDE - 4 + sx * 4;
    const int gy0 = by * TH * STRIDE - 1;

    float acc[4][CO_PER];
    {
        float bv[CO_PER];
#pragma unroll
        for (int jj = 0; jj < CO_PER; jj += 4) {
            float4 b4 = *(const float4*)(bias + cg * CO_PER + jj);
            bv[jj] = b4.x; bv[jj + 1] = b4.y; bv[jj + 2] = b4.z; bv[jj + 3] = b4.w;
        }
#pragma unroll
        for (int p = 0; p < 4; ++p)
#pragma unroll
            for (int j = 0; j < CO_PER; ++j) acc[p][j] = bv[j];
    }

    for (int ch = 0; ch < CIN; ch += CCHUNK) {
        if (sact) {
            const int gy = gy0 + sr;
            const bool yok = (unsigned)gy < (unsigned)inH;
            const bool xfull = (gxs >= 0) && (gxs + 3 < inW);
#pragma unroll
            for (int c = 0; c < CCHUNK; ++c) {
                const int gc = ch + c;
                const float* row = (gc < split)
                    ? in0 + off0 + ((long)gc * inH + gy) * inW
                    : in1 + off1 + ((long)(gc - split) * inH + gy) * inW;
                float4 v = {0.f, 0.f, 0.f, 0.f};
                if (yok) {
                    if (xfull) {
                        v = *(const float4*)(row + gxs);
                    } else {
                        float t[4];
#pragma unroll
                        for (int k = 0; k < 4; ++k) {
                            int gx = gxs + k;
                            t[k] = ((unsigned)gx < (unsigned)inW) ? row[gx] : 0.f;
                        }
                        v = {t[0], t[1], t[2], t[3]};
                    }
                }
                float* dst = &tile[c][sr][sx * 4];
                dst[0] = v.x; dst[1] = v.y; dst[2] = v.z; dst[3] = v.w;
            }
        }
#pragma unroll 1
        for (int wc = 0; wc < CCHUNK; wc += WCH) {
            {
                const float4* wsrc = (const float4*)(wT + (long)(ch + wc) * 9 * COUT);
                float4* wdst = (float4*)wlds;
                constexpr int CNT = WCH * 9 * COUT / 4;
                for (int i = tid; i < CNT; i += 256) wdst[i] = wsrc[i];
            }
            __syncthreads();
#pragma unroll 1
            for (int c = 0; c < WCH; ++c) {
#pragma unroll
                for (int ky = 0; ky < 3; ++ky) {
                    const int ty = yy * STRIDE + ky;
                    const int tx0 = xg * 4 * STRIDE + 3;
                    float xw[WIN];
#pragma unroll
                    for (int i = 0; i < WIN; ++i) xw[i] = tile[wc + c][ty][tx0 + i];
#pragma unroll
                    for (int dx = 0; dx < 3; ++dx) {
                        const float* wp = wlds + ((c * 3 + ky) * 3 + dx) * COUT + cg * CO_PER;
                        float wv[CO_PER];
#pragma unroll
                        for (int jj = 0; jj < CO_PER; jj += 4) {
                            float4 w4 = *(const float4*)(wp + jj);
                            wv[jj] = w4.x; wv[jj + 1] = w4.y; wv[jj + 2] = w4.z; wv[jj + 3] = w4.w;
                        }
#pragma unroll
                        for (int p = 0; p < 4; ++p) {
                            float xv = xw[p * STRIDE + dx];
#pragma unroll
                            for (int j = 0; j < CO_PER; ++j) acc[p][j] = fmaf(xv, wv[j], acc[p][j]);
                        }
                    }
                }
            }
            __syncthreads();
        }
    }

    const int ox0 = bx * TW + xg * 4;
    const int oy = by * TH + yy;
#pragma unroll
    for (int j = 0; j < CO_PER; ++j) {
        int co = cg * CO_PER + j;
        float4 o;
        o.x = fmaxf(acc[0][j], 0.f);
        o.y = fmaxf(acc[1][j], 0.f);
        o.z = fmaxf(acc[2][j], 0.f);
        o.w = fmaxf(acc[3][j], 0.f);
        *(float4*)(outp + ((long)co * outH + oy) * outW + ox0) = o;
    }
}

// ---------------- spatial mean over 96x96 plane, z-batched ----------------
__global__ __launch_bounds__(256) void pool_k(const float* __restrict__ enc3base,
                                              long zstride,
                                              float* __restrict__ meanout) {
    int z = blockIdx.x >> 6;
    int c = blockIdx.x & 63;
    const float* p = enc3base + (long)z * zstride + (long)c * 9216;
    float s = 0.f;
    for (int i = threadIdx.x; i < 9216; i += 256) s += p[i];
    __shared__ float red[256];
    red[threadIdx.x] = s;
    __syncthreads();
    for (int o = 128; o > 0; o >>= 1) {
        if (threadIdx.x < o) red[threadIdx.x] += red[threadIdx.x + o];
        __syncthreads();
    }
    if (threadIdx.x == 0) meanout[z * 64 + c] = red[0] * (1.f / 9216.f);
}

// ---------------- task embedding + te-derived constants ----------------
__global__ __launch_bounds__(256) void prep_te_k(
    const float* __restrict__ means, const float* __restrict__ lw,
    const float* __restrict__ lb, const float* __restrict__ tauw,
    const float* __restrict__ taub, const float* __restrict__ w1,
    const float* __restrict__ b1,
    float* __restrict__ tauc, float* __restrict__ wsum,
    float* __restrict__ bias2) {
    __shared__ float tes[64];
    int t = threadIdx.x;
    if (t < 64) {
        float s = 0.f;
        for (int d = 0; d < 4; ++d)
            for (int c = 0; c < 64; ++c) s += means[d * 64 + c] * lw[t * 64 + c];
        tes[t] = lb[t] + 0.25f * s;
    }
    __syncthreads();
    if (t < 32) {
        float s = taub[t];
        for (int e = 0; e < 64; ++e) s += tauw[t * 96 + 32 + e] * tes[e];
        tauc[t] = s;
    }
    for (int i = t; i < 288; i += 256) {
        int co = i % 32;
        int k = i / 32;
        float s = 0.f;
        for (int e = 0; e < 64; ++e) s += w1[((co * 96) + 32 + e) * 9 + k] * tes[e];
        wsum[i] = s;
    }
    __syncthreads();
    if (t < 32) {
        float s = b1[t];
        for (int k = 0; k < 9; ++k) s += wsum[k * 32 + t];
        bias2[t] = s;  // b1 + full 9-tap te sum (border fixed in nca_fuse_k)
    }
}

// ---------------- fused NCA 1x1s + gate (reads h1_raw, writes s_new IN PLACE) ----------------
// Block owns 64 px: h and s_old staged in LDS once (16 KB); threads are
// (px, coutgroup-of-8) pairs -> per-thread state = accd[8]+acct[8] (~30 VGPR,
// statically indexed). R18/R19 proved the 1px x 32co register structure
// spills catastrophically (1.13 GB scratch writes); this keeps the px-reuse
// in LDS instead. h1 = relu(h1_raw - border_corr).
__global__ __launch_bounds__(256, 4) void nca_fuse_k(
    const float* __restrict__ sold, float* __restrict__ hb,  // h1_raw in, s_new out
    const float* __restrict__ wsum, const float* __restrict__ w2T,
    const float* __restrict__ b2, const float* __restrict__ tauT,
    const float* __restrict__ tauc) {
    __shared__ float hs[32][64], ss[32][64];  // 16,384 B
    __shared__ float sw2[1024], stu[1024], swv[288], sb2[32], stc[32];
    const int tid = threadIdx.x;
    const long px0 = (long)blockIdx.x * 64;
    for (int i = tid; i < 1024; i += 256) {
        sw2[i] = w2T[i];
        stu[i] = tauT[i];
    }
    for (int i = tid; i < 288; i += 256) swv[i] = wsum[i];
    if (tid < 32) {
        sb2[tid] = b2[tid];
        stc[tid] = tauc[tid];
    }
    // stage h and s_old: 32 ch x 64 px each (coalesced 256B rows)
#pragma unroll
    for (int i = tid; i < 2048; i += 256) {
        const int ch = i >> 6;
        const int p = i & 63;
        hs[ch][p] = hb[(long)ch * HW + px0 + p];
        ss[ch][p] = sold[(long)ch * HW + px0 + p];
    }
    __syncthreads();

    const int p = tid & 63;
    const int cog = tid >> 6;  // 0..3 -> couts [cog*8, cog*8+8)
    const long px = px0 + p;
    const int y = (int)(px / 384);
    const int x = (int)(px - (long)y * 384);
    unsigned mask = 0;
#pragma unroll
    for (int ky = 0; ky < 3; ++ky)
#pragma unroll
        for (int kx = 0; kx < 3; ++kx) {
            int yy = y - 1 + ky, xx = x - 1 + kx;
            if ((unsigned)yy < 384u && (unsigned)xx < 384u) mask |= 1u << (ky * 3 + kx);
        }
    const bool interior = (mask == 0x1FFu);

    float accd[8], acct[8];
#pragma unroll
    for (int j = 0; j < 8; ++j) {
        accd[j] = sb2[cog * 8 + j];
        acct[j] = stc[cog * 8 + j];
    }
#pragma unroll
    for (int ci = 0; ci < 32; ++ci) {
        float h = hs[ci][p];
        float sv = ss[ci][p];
        if (!interior) {
#pragma unroll
            for (int t = 0; t < 9; ++t)
                if (!((mask >> t) & 1u)) h -= swv[t * 32 + ci];
        }
        h = fmaxf(h, 0.f);
        const float* wd = sw2 + ci * 32 + cog * 8;
        const float* wt = stu + ci * 32 + cog * 8;
#pragma unroll
        for (int j = 0; j < 8; ++j) {
            accd[j] = fmaf(h, wd[j], accd[j]);
            acct[j] = fmaf(sv, wt[j], acct[j]);
        }
    }
#pragma unroll
    for (int j = 0; j < 8; ++j) {
        const int co = cog * 8 + j;
        float beta = 1.f / (1.f + __expf(-acct[j]));
        hb[(long)co * HW + px] = beta * ss[co][p] + (1.f - beta) * accd[j];
    }
}

// ---------------- decode 1x1 -> fp32 output ----------------
__global__ __launch_bounds__(256) void dec_k(const float* __restrict__ st,
                                             const float* __restrict__ dT,
                                             const float* __restrict__ db,
                                             float* __restrict__ out) {
    int gid = blockIdx.x * 256 + threadIdx.x;
    long px0 = (long)gid * 2;
    float acc[11][2];
#pragma unroll
    for (int co = 0; co < 11; ++co) {
        float b = db[co];
        acc[co][0] = b;
        acc[co][1] = b;
    }
    for (int ci = 0; ci < 32; ++ci) {
        float2 s2 = *(const float2*)(st + (long)ci * HW + px0);
        const float* wp = dT + ci * 12;
        float4 w0 = *(const float4*)wp, w1 = *(const float4*)(wp + 4), w2 = *(const float4*)(wp + 8);
        float wv[12] = {w0.x, w0.y, w0.z, w0.w, w1.x, w1.y, w1.z, w1.w, w2.x, w2.y, w2.z, w2.w};
#pragma unroll
        for (int co = 0; co < 11; ++co) {
            acc[co][0] = fmaf(s2.x, wv[co], acc[co][0]);
            acc[co][1] = fmaf(s2.y, wv[co], acc[co][1]);
        }
    }
#pragma unroll
    for (int co = 0; co < 11; ++co) {
        float2 o = {acc[co][0], acc[co][1]};
        *(float2*)(out + (long)co * HW + px0) = o;
    }
}

extern "C" void kernel_launch(void* const* d_in, const int* in_sizes, int n_in,
                              void* d_out, int out_size, void* d_ws, size_t ws_size,
                              hipStream_t stream) {
    float* out = (float*)d_out;
    const float* demo_in = (const float*)d_in[0];
    const float* demo_out = (const float*)d_in[1];
    const float* test_in = (const float*)d_in[2];
    const float* enc_w1 = (const float*)d_in[3];
    const float* enc_b1 = (const float*)d_in[4];
    const float* enc_w2 = (const float*)d_in[5];
    const float* enc_b2 = (const float*)d_in[6];
    const float* enc_w3 = (const float*)d_in[7];
    const float* enc_b3 = (const float*)d_in[8];
    const float* enc_lw = (const float*)d_in[9];
    const float* enc_lb = (const float*)d_in[10];
    const float* stem_w = (const float*)d_in[11];
    const float* stem_b = (const float*)d_in[12];
    const float* upd_w1 = (const float*)d_in[13];
    const float* upd_b1 = (const float*)d_in[14];
    const float* upd_w2 = (const float*)d_in[15];
    const float* upd_b2 = (const float*)d_in[16];
    const float* tau_w = (const float*)d_in[17];
    const float* tau_b = (const float*)d_in[18];
    const float* dec_w = (const float*)d_in[19];
    const float* dec_b = (const float*)d_in[20];

    // ---- workspace layout (floats) ----
    float* Wb = (float*)d_ws;
    float* wT_D = Wb + 0;        // 3744 (stem fp32)
    float* w2T  = Wb + 3744;     // 1024
    float* tauT = Wb + 4768;     // 1024
    float* decT = Wb + 5792;     // 384
    float* tauc = Wb + 6176;     // 32
    float* wsum = Wb + 6208;     // 288
    float* means = Wb + 6496;    // 256
    float* bias2 = Wb + 6752;    // 32
    unsigned short* wB1 = (unsigned short*)(Wb + 6784);   // 9*32*32 bf16 (4608 f)
    unsigned short* wB2 = (unsigned short*)(Wb + 11392);  // 9*64*32 (9216 f)
    unsigned short* wB3 = (unsigned short*)(Wb + 20608);  // 9*64*64 (18432 f)
    unsigned short* wBE = (unsigned short*)(Wb + 39040);  // 9*32*32 (4608 f)
    float* big = Wb + 45056;

    const long PD = 7667712;  // per-demo floats (enc1+enc2+enc3)
    const long E1 = 4718592, E2 = 2359296;
    size_t wsf = ws_size / 4;
    int NZ = 1;
    if (wsf >= 45056 + 4 * (size_t)PD) NZ = 4;
    else if (wsf >= 45056 + 2 * (size_t)PD) NZ = 2;

    // ---- fp32 weight transposes (stem + 1x1s + dec) ----
    TJobs J;
    {
        const float* srcs[5] = {stem_w, upd_w2, tau_w, dec_w, dec_w};
        float* dsts[5] = {wT_D, w2T, tauT, decT, decT};
        int couts[5] = {32, 32, 32, 11, 0};
        int cintots[5] = {13, 32, 96, 32, 32};
        int ks[5] = {9, 1, 1, 1, 1};
        int cinsels[5] = {13, 32, 32, 32, 0};
        int coutps[5] = {32, 32, 32, 12, 12};
        int acc0 = 0;
        for (int j = 0; j < 5; ++j) {
            J.src[j] = srcs[j]; J.dst[j] = dsts[j];
            J.cout[j] = couts[j]; J.cintot[j] = cintots[j];
            J.k[j] = ks[j]; J.coutp[j] = coutps[j];
            J.start[j] = acc0;
            acc0 += cinsels[j] * ks[j] * coutps[j];
        }
        J.start[5] = acc0;
        transpose_all_k<<<(acc0 + 255) / 256, 256, 0, stream>>>(J);
    }
    // ---- bf16 MFMA weights (encoder convs + nca 3x3 state part) ----
    WJobs W;
    {
        const float* srcs[4] = {enc_w1, enc_w2, enc_w3, upd_w1};
        unsigned short* dsts[4] = {wB1, wB2, wB3, wBE};
        int couts[4] = {32, 64, 64, 32};
        int cins[4] = {26, 32, 64, 32};
        int cintots[4] = {26, 32, 64, 96};
        int cinps[4] = {32, 32, 64, 32};
        int acc0 = 0;
        for (int j = 0; j < 4; ++j) {
            W.src[j] = srcs[j]; W.dst[j] = dsts[j];
            W.cout[j] = couts[j]; W.cin[j] = cins[j];
            W.cintot[j] = cintots[j]; W.cinp[j] = cinps[j];
            W.start[j] = acc0;
            acc0 += 9 * couts[j] * cinps[j];
        }
        W.start[4] = acc0;
        transpose_wbf_k<<<(acc0 + 255) / 256, 256, 0, stream>>>(W);
    }

    // ---- encoder (bf16 MFMA), NZ demos per launch ----
    for (int d0 = 0; d0 < 4; d0 += NZ) {
        mfma_conv_k<26, 40, 32, 1, 64, 4, 5, true><<<dim3(6, 96, NZ), 256, 0, stream>>>(
            demo_in, demo_out, 13, (long)d0 * 13 * HW, (long)d0 * 13 * HW,
            13L * HW, 13L * HW, 384, 384, wB1, enc_b1, big, PD);
        mfma_conv_k<32, 40, 64, 2, 32, 2, 5, true><<<dim3(6, 96, NZ), 256, 0, stream>>>(
            big, big, 32, 0, 0, PD, PD, 384, 384, wB2, enc_b2, big + E1, PD);
        mfma_conv_k<64, 72, 64, 2, 16, 2, 5, true><<<dim3(6, 48, NZ), 256, 0, stream>>>(
            big + E1, big + E1, 64, 0, 0, PD, PD, 192, 192, wB3, enc_b3,
            big + E1 + E2, PD);
        pool_k<<<64 * NZ, 256, 0, stream>>>(big + E1 + E2, PD, means + d0 * 64);
    }
    prep_te_k<<<1, 256, 0, stream>>>(means, enc_lw, enc_lb, tau_w, tau_b, upd_w1,
                                     upd_b1, tauc, wsum, bias2);

    // ---- stem (fp32 exact) -> sA ----
    float* sA = big;
    float* sX = big + E1;
    conv3x3_k<13, 13, 13, 32, 1, 32, 8, 5><<<dim3(12, 48, 1), 256, 0, stream>>>(
        test_in, test_in, 13, 0, 0, 0, 0, 384, 384, wT_D, stem_b, sA, 0);

    // ---- 8 NCA steps: A) mfma 3x3 -> h1_raw(b)   B) fused 1x1s+gate (b in place)
    float* a = sA;
    float* b = sX;
    for (int s = 0; s < 8; ++s) {
        mfma_conv_k<32, 40, 32, 1, 32, 8, 5, false><<<dim3(12, 48, 1), 256, 0, stream>>>(
            a, a, 32, 0, 0, 0, 0, 384, 384, wBE, bias2, b, 0);
        nca_fuse_k<<<2304, 256, 0, stream>>>(a, b, wsum, w2T, upd_b2, tauT, tauc);
        float* t = a; a = b; b = t;
    }
    dec_k<<<288, 256, 0, stream>>>(a, decT, dec_b, out);
}

// Round 21
// 504.358 us; speedup vs baseline: 12.3472x; 8.1723x over previous
//
#include <hip/hip_runtime.h>

#define HW 147456  // 384*384

typedef __attribute__((ext_vector_type(8))) short bf16x8;
typedef __attribute__((ext_vector_type(4))) float f32x4;

__device__ __forceinline__ float bf2f(unsigned short u) {
    return __uint_as_float(((unsigned)u) << 16);
}
__device__ __forceinline__ unsigned short f2bf(float f) {
    unsigned u = __float_as_uint(f);
    return (unsigned short)((u + 0x7fffu + ((u >> 16) & 1u)) >> 16);  // RNE
}

// ---------------- fp32 weight transpose: w[COUT][CINTOT][K] -> wT[cin][k][COUTP] ----------------
struct TJobs {
    const float* src[5];
    float* dst[5];
    int cout[5], cintot[5], k[5], coutp[5];
    int start[6];
};

__global__ __launch_bounds__(256) void transpose_all_k(TJobs J) {
    int gid = blockIdx.x * 256 + threadIdx.x;
    if (gid >= J.start[5]) return;
    int j = 0;
#pragma unroll
    for (int t = 1; t < 5; ++t)
        if (gid >= J.start[t]) j = t;
    int li = gid - J.start[j];
    int coutp = J.coutp[j], K = J.k[j];
    int co = li % coutp;
    int kk = (li / coutp) % K;
    int cin = li / (coutp * K);
    J.dst[j][li] = (co < J.cout[j]) ? J.src[j][((co * J.cintot[j]) + cin) * K + kk] : 0.f;
}

// ---------------- bf16 weight prep for MFMA: w[COUT][CINTOT][9] -> wB[9][COUT][CINP] ----------------
struct WJobs {
    const float* src[4];
    unsigned short* dst[4];
    int cout[4], cin[4], cintot[4], cinp[4];
    int start[5];
};

__global__ __launch_bounds__(256) void transpose_wbf_k(WJobs J) {
    int gid = blockIdx.x * 256 + threadIdx.x;
    if (gid >= J.start[4]) return;
    int j = 0;
#pragma unroll
    for (int t = 1; t < 4; ++t)
        if (gid >= J.start[t]) j = t;
    int li = gid - J.start[j];
    int cinp = J.cinp[j];
    int ci = li % cinp;
    int co = (li / cinp) % J.cout[j];
    int tap = li / (cinp * J.cout[j]);
    float v = (ci < J.cin[j]) ? J.src[j][((co * J.cintot[j]) + ci) * 9 + tap] : 0.f;
    J.dst[j][li] = f2bf(v);
}

// ---------------- bf16 MFMA implicit-GEMM 3x3 conv, pad=1, optional ReLU ----------------
template <int CIN, int CP, int COUT, int S, int OX, int OY, int MW, bool RELU>
__global__ __launch_bounds__(256, MW) void mfma_conv_k(
    const float* __restrict__ in0, const float* __restrict__ in1, int split,
    long off0base, long off1base, long zs0, long zs1, int inW, int inH,
    const unsigned short* __restrict__ wB,  // [9][COUT][CINK] bf16
    const float* __restrict__ bias,
    float* __restrict__ out, long outZS) {
    constexpr int XT = (OX - 1) * S + 3;
    constexpr int YT = (OY - 1) * S + 3;
    constexpr int CINK = (CIN + 31) & ~31;
    constexpr int KST = CINK / 32;
    constexpr int NCG = COUT / 16;
    constexpr int NTX = OX / 16;
    constexpr int NSP = NTX * OY;
    constexpr int NTASK = NSP * NCG;
    constexpr int NT4 = NTASK / 4;
    constexpr int NSLOT = YT * XT;
    static_assert(NTASK % 4 == 0, "tasks per wave");
    static_assert(NSP % NT4 == 0, "wave must own a single cout-group");
    static_assert(CP % 8 == 0 && CP >= CINK, "LDS cin pad");
    static_assert((CP / 8) % 2 == 1, "odd chunk stride for bank spread");
    __shared__ __align__(16) unsigned short tile[NSLOT * CP];
    const int tid = threadIdx.x;
    const int bx = blockIdx.x, by = blockIdx.y, z = blockIdx.z;
    const long o0 = off0base + (long)z * zs0;
    const long o1 = off1base + (long)z * zs1;
    const int outW = inW / S, outH = inH / S;
    const int gx0 = bx * OX * S - 1;
    const int gy0 = by * OY * S - 1;

#pragma unroll 1
    for (int s = tid; s < NSLOT; s += 256) {
        const int sy = s / XT;
        const int lx = s - sy * XT;
        const int gy = gy0 + sy;
        const int gx = gx0 + lx;
        const bool ok = ((unsigned)gy < (unsigned)inH) && ((unsigned)gx < (unsigned)inW);
        const long pix = (long)gy * inW + gx;
#pragma unroll
        for (int h = 0; h < CINK / 8; ++h) {
            bf16x8 v;
#pragma unroll
            for (int e = 0; e < 8; ++e) {
                const int c = h * 8 + e;
                float f = 0.f;
                if (c < CIN && ok) {
                    const float* base = (c < split)
                        ? in0 + o0 + (long)c * inH * inW
                        : in1 + o1 + (long)(c - split) * inH * inW;
                    f = base[pix];
                }
                v[e] = (short)f2bf(f);
            }
            *(bf16x8*)(tile + s * CP + h * 8) = v;
        }
    }
    __syncthreads();

    const int wv = tid >> 6;
    const int l = tid & 63;
    const int ln = l & 15;
    const int lk = l >> 4;
    const int cg = (wv * NT4) / NSP;
    bf16x8 bfr[9 * KST];
#pragma unroll
    for (int tap = 0; tap < 9; ++tap)
#pragma unroll
        for (int h = 0; h < KST; ++h)
            bfr[tap * KST + h] = *(const bf16x8*)(wB + ((long)(tap * COUT + cg * 16 + ln)) * CINK + h * 32 + lk * 8);
    const float bv = bias[cg * 16 + ln];
#pragma unroll 1
    for (int t = 0; t < NT4; ++t) {
        const int sp = wv * NT4 + t - cg * NSP;
        const int tx = sp % NTX;
        const int ty = sp / NTX;
        f32x4 acc;
        acc[0] = bv; acc[1] = bv; acc[2] = bv; acc[3] = bv;
#pragma unroll
        for (int ky = 0; ky < 3; ++ky) {
#pragma unroll
            for (int kx = 0; kx < 3; ++kx) {
                const int yb = ty * S + ky;
                const int xb = (tx * 16 + ln) * S + kx;
                const unsigned short* ap = tile + (yb * XT + xb) * CP + lk * 8;
#pragma unroll
                for (int h = 0; h < KST; ++h) {
                    bf16x8 a = *(const bf16x8*)(ap + h * 32);
                    acc = __builtin_amdgcn_mfma_f32_16x16x32_bf16(a, bfr[(ky * 3 + kx) * KST + h], acc, 0, 0, 0);
                }
            }
        }
        const int ox = bx * OX + tx * 16 + lk * 4;
        const int oy = by * OY + ty;
        float4 o;
        if constexpr (RELU) {
            o.x = fmaxf(acc[0], 0.f);
            o.y = fmaxf(acc[1], 0.f);
            o.z = fmaxf(acc[2], 0.f);
            o.w = fmaxf(acc[3], 0.f);
        } else {
            o.x = acc[0]; o.y = acc[1]; o.z = acc[2]; o.w = acc[3];
        }
        *(float4*)(out + (long)z * outZS + ((long)(cg * 16 + ln) * outH + oy) * outW + ox) = o;
    }
}

// ---------------- fp32 LDS-tiled 3x3 conv (stem only: precision-critical) ----------------
template <int CIN, int CCHUNK, int WCH, int COUT, int STRIDE, int TW, int CO_PER, int MW>
__global__ __launch_bounds__(256, MW) void conv3x3_k(
    const float* __restrict__ in0, const float* __restrict__ in1, int split,
    long inOff0, long inOff1, long zs0, long zs1, int inW, int inH,
    const float* __restrict__ wT, const float* __restrict__ bias,
    float* __restrict__ out, long outZS) {
    constexpr int NCG = COUT / CO_PER;
    constexpr int NPXG = 256 / NCG;
    constexpr int NXG = TW / 4;
    constexpr int TH = NPXG / NXG;
    constexpr int INW = (TW - 1) * STRIDE + 3;
    constexpr int INH = (TH - 1) * STRIDE + 3;
    constexpr int WIN = 3 * STRIDE + 3;
    constexpr int XV = (INW + 6) / 4;
    constexpr int LDSW = XV * 4 + 1;
    constexpr int SLOTS = INH * XV;
    static_assert(NPXG % NXG == 0 && NPXG * NCG == 256, "thread mapping");
    static_assert(CIN % CCHUNK == 0 && CCHUNK % WCH == 0, "chunking");
    static_assert(SLOTS <= 256, "staging slots");
    __shared__ float tile[CCHUNK][INH][LDSW];
    __shared__ __align__(16) float wlds[WCH * 9 * COUT];
    const int tid = threadIdx.x;
    const int cg = tid / NPXG;
    const int pg = tid % NPXG;
    const int xg = pg % NXG;
    const int yy = pg / NXG;
    const int bx = blockIdx.x, by = blockIdx.y, z = blockIdx.z;
    const int outW = inW / STRIDE, outH = inH / STRIDE;
    const long off0 = inOff0 + (long)z * zs0;
    const long off1 = inOff1 + (long)z * zs1;
    float* outp = out + (long)z * outZS;
    const bool sact = tid < SLOTS;
    const int sr = tid / XV;
    const int sx = tid - sr * XV;
    const int gxs = bx * TW * STRIDE - 4 + sx * 4;
    const int gy0 = by * TH * STRIDE - 1;

    float acc[4][CO_PER];
    {
        float bv[CO_PER];
#pragma unroll
        for (int jj = 0; jj < CO_PER; jj += 4) {
            float4 b4 = *(const float4*)(bias + cg * CO_PER + jj);
            bv[jj] = b4.x; bv[jj + 1] = b4.y; bv[jj + 2] = b4.z; bv[jj + 3] = b4.w;
        }
#pragma unroll
        for (int p = 0; p < 4; ++p)
#pragma unroll
            for (int j = 0; j < CO_PER; ++j) acc[p][j] = bv[j];
    }

    for (int ch = 0; ch < CIN; ch += CCHUNK) {
        if (sact) {
            const int gy = gy0 + sr;
            const bool yok = (unsigned)gy < (unsigned)inH;
            const bool xfull = (gxs >= 0) && (gxs + 3 < inW);
#pragma unroll
            for (int c = 0; c < CCHUNK; ++c) {
                const int gc = ch + c;
                const float* row = (gc < split)
                    ? in0 + off0 + ((long)gc * inH + gy) * inW
                    : in1 + off1 + ((long)(gc - split) * inH + gy) * inW;
                float4 v = {0.f, 0.f, 0.f, 0.f};
                if (yok) {
                    if (xfull) {
                        v = *(const float4*)(row + gxs);
                    } else {
                        float t[4];
#pragma unroll
                        for (int k = 0; k < 4; ++k) {
                            int gx = gxs + k;
                            t[k] = ((unsigned)gx < (unsigned)inW) ? row[gx] : 0.f;
                        }
                        v = {t[0], t[1], t[2], t[3]};
                    }
                }
                float* dst = &tile[c][sr][sx * 4];
                dst[0] = v.x; dst[1] = v.y; dst[2] = v.z; dst[3] = v.w;
            }
        }
#pragma unroll 1
        for (int wc = 0; wc < CCHUNK; wc += WCH) {
            {
                const float4* wsrc = (const float4*)(wT + (long)(ch + wc) * 9 * COUT);
                float4* wdst = (float4*)wlds;
                constexpr int CNT = WCH * 9 * COUT / 4;
                for (int i = tid; i < CNT; i += 256) wdst[i] = wsrc[i];
            }
            __syncthreads();
#pragma unroll 1
            for (int c = 0; c < WCH; ++c) {
#pragma unroll
                for (int ky = 0; ky < 3; ++ky) {
                    const int ty = yy * STRIDE + ky;
                    const int tx0 = xg * 4 * STRIDE + 3;
                    float xw[WIN];
#pragma unroll
                    for (int i = 0; i < WIN; ++i) xw[i] = tile[wc + c][ty][tx0 + i];
#pragma unroll
                    for (int dx = 0; dx < 3; ++dx) {
                        const float* wp = wlds + ((c * 3 + ky) * 3 + dx) * COUT + cg * CO_PER;
                        float wv[CO_PER];
#pragma unroll
                        for (int jj = 0; jj < CO_PER; jj += 4) {
                            float4 w4 = *(const float4*)(wp + jj);
                            wv[jj] = w4.x; wv[jj + 1] = w4.y; wv[jj + 2] = w4.z; wv[jj + 3] = w4.w;
                        }
#pragma unroll
                        for (int p = 0; p < 4; ++p) {
                            float xv = xw[p * STRIDE + dx];
#pragma unroll
                            for (int j = 0; j < CO_PER; ++j) acc[p][j] = fmaf(xv, wv[j], acc[p][j]);
                        }
                    }
                }
            }
            __syncthreads();
        }
    }

    const int ox0 = bx * TW + xg * 4;
    const int oy = by * TH + yy;
#pragma unroll
    for (int j = 0; j < CO_PER; ++j) {
        int co = cg * CO_PER + j;
        float4 o;
        o.x = fmaxf(acc[0][j], 0.f);
        o.y = fmaxf(acc[1][j], 0.f);
        o.z = fmaxf(acc[2][j], 0.f);
        o.w = fmaxf(acc[3][j], 0.f);
        *(float4*)(outp + ((long)co * outH + oy) * outW + ox0) = o;
    }
}

// ---------------- spatial mean over 96x96 plane, z-batched ----------------
__global__ __launch_bounds__(256) void pool_k(const float* __restrict__ enc3base,
                                              long zstride,
                                              float* __restrict__ meanout) {
    int z = blockIdx.x >> 6;
    int c = blockIdx.x & 63;
    const float* p = enc3base + (long)z * zstride + (long)c * 9216;
    float s = 0.f;
    for (int i = threadIdx.x; i < 9216; i += 256) s += p[i];
    __shared__ float red[256];
    red[threadIdx.x] = s;
    __syncthreads();
    for (int o = 128; o > 0; o >>= 1) {
        if (threadIdx.x < o) red[threadIdx.x] += red[threadIdx.x + o];
        __syncthreads();
    }
    if (threadIdx.x == 0) meanout[z * 64 + c] = red[0] * (1.f / 9216.f);
}

// ---------------- task embedding + te-derived constants ----------------
__global__ __launch_bounds__(256) void prep_te_k(
    const float* __restrict__ means, const float* __restrict__ lw,
    const float* __restrict__ lb, const float* __restrict__ tauw,
    const float* __restrict__ taub, const float* __restrict__ w1,
    const float* __restrict__ b1,
    float* __restrict__ tauc, float* __restrict__ wsum,
    float* __restrict__ bias2) {
    __shared__ float tes[64];
    int t = threadIdx.x;
    if (t < 64) {
        float s = 0.f;
        for (int d = 0; d < 4; ++d)
            for (int c = 0; c < 64; ++c) s += means[d * 64 + c] * lw[t * 64 + c];
        tes[t] = lb[t] + 0.25f * s;
    }
    __syncthreads();
    if (t < 32) {
        float s = taub[t];
        for (int e = 0; e < 64; ++e) s += tauw[t * 96 + 32 + e] * tes[e];
        tauc[t] = s;
    }
    for (int i = t; i < 288; i += 256) {
        int co = i % 32;
        int k = i / 32;
        float s = 0.f;
        for (int e = 0; e < 64; ++e) s += w1[((co * 96) + 32 + e) * 9 + k] * tes[e];
        wsum[i] = s;
    }
    __syncthreads();
    if (t < 32) {
        float s = b1[t];
        for (int k = 0; k < 9; ++k) s += wsum[k * 32 + t];
        bias2[t] = s;  // b1 + full 9-tap te sum (border fixed in nca_fuse_k)
    }
}

// ---------------- fused NCA 1x1s + gate (reads h1_raw, writes s_new IN PLACE) ----------------
// R15's PROVEN register shape: cg=tid>>5 (8 groups x 4 couts), pg=tid&31
// (32 x 4 px), accd[4][4]+acct[4][4] statically indexed (52-88 VGPR, no
// scratch in R15-R17). Block owns 128 px (128 | 384 -> y block-uniform);
// h1 staged bf16 (same precision as R15's h1s), s_old staged fp32.
// R18-R20's fresh per-thread-array designs all generated ~1 GB scratch
// traffic; this reuses the structure the compiler already handled well.
__global__ __launch_bounds__(256, 4) void nca_fuse_k(
    const float* __restrict__ sold, float* __restrict__ hb,  // h1_raw in, s_new out
    const float* __restrict__ wsum, const float* __restrict__ w2T,
    const float* __restrict__ b2, const float* __restrict__ tauT,
    const float* __restrict__ tauc) {
    __shared__ unsigned short h1s[32][136];          //  8,704 B (bf16)
    __shared__ __align__(16) float ss[32][132];      // 16,896 B
    __shared__ __align__(16) float sw2[1024];        //  4,096 B
    __shared__ __align__(16) float stu[1024];        //  4,096 B
    __shared__ float swv[288], sb2[32], stc[32];     //  1,408 B
    const int tid = threadIdx.x;
    const long px0 = (long)blockIdx.x * 128;
    for (int i = tid; i < 1024; i += 256) {
        sw2[i] = w2T[i];
        stu[i] = tauT[i];
    }
    for (int i = tid; i < 288; i += 256) swv[i] = wsum[i];
    if (tid < 32) {
        sb2[tid] = b2[tid];
        stc[tid] = tauc[tid];
    }
    // y is block-uniform (128 divides 384)
    const int yrow = (int)(px0 / 384);
    const int xbase = (int)(px0 - (long)yrow * 384);
    const bool ytop = (yrow == 0), ybot = (yrow == 383);
    // stage h (border-corrected, relu, bf16) and s_old (fp32): 32ch x 32 vec4
#pragma unroll 1
    for (int i = tid; i < 1024; i += 256) {
        const int ch = i >> 5;
        const int p4 = i & 31;
        float4 h4 = *(const float4*)(hb + (long)ch * HW + px0 + p4 * 4);
        float4 s4 = *(const float4*)(sold + (long)ch * HW + px0 + p4 * 4);
        float hv[4] = {h4.x, h4.y, h4.z, h4.w};
        unsigned short ho[4];
#pragma unroll
        for (int e = 0; e < 4; ++e) {
            const int x = xbase + p4 * 4 + e;
            float h = hv[e];
            const bool xl = (x == 0), xr = (x == 383);
            if (xl | xr | ytop | ybot) {
#pragma unroll
                for (int ky = 0; ky < 3; ++ky)
#pragma unroll
                    for (int kx = 0; kx < 3; ++kx) {
                        bool inval = (ky == 0 && ytop) || (ky == 2 && ybot) ||
                                     (kx == 0 && xl) || (kx == 2 && xr);
                        if (inval) h -= swv[(ky * 3 + kx) * 32 + ch];
                    }
            }
            ho[e] = f2bf(fmaxf(h, 0.f));
        }
        unsigned short* hd = &h1s[ch][p4 * 4];
        hd[0] = ho[0]; hd[1] = ho[1]; hd[2] = ho[2]; hd[3] = ho[3];
        *(float4*)(&ss[ch][p4 * 4]) = s4;
    }
    __syncthreads();

    const int cg = tid >> 5;  // 4 couts
    const int pg = tid & 31;  // 4 px
    const int p0 = pg * 4;
    float accd[4][4], acct[4][4];
    {
        float dv[4], tv[4];
#pragma unroll
        for (int j = 0; j < 4; ++j) {
            dv[j] = sb2[cg * 4 + j];
            tv[j] = stc[cg * 4 + j];
        }
#pragma unroll
        for (int p = 0; p < 4; ++p)
#pragma unroll
            for (int j = 0; j < 4; ++j) { accd[p][j] = dv[j]; acct[p][j] = tv[j]; }
    }
#pragma unroll 2
    for (int ci = 0; ci < 32; ++ci) {
        float hv[4], sv[4];
#pragma unroll
        for (int p = 0; p < 4; ++p) {
            hv[p] = bf2f(h1s[ci][p0 + p]);
            sv[p] = ss[ci][p0 + p];
        }
        float4 wd4 = *(const float4*)(sw2 + ci * 32 + cg * 4);
        float4 wt4 = *(const float4*)(stu + ci * 32 + cg * 4);
        float wdv[4] = {wd4.x, wd4.y, wd4.z, wd4.w};
        float wtv[4] = {wt4.x, wt4.y, wt4.z, wt4.w};
#pragma unroll
        for (int p = 0; p < 4; ++p) {
#pragma unroll
            for (int j = 0; j < 4; ++j) {
                accd[p][j] = fmaf(hv[p], wdv[j], accd[p][j]);
                acct[p][j] = fmaf(sv[p], wtv[j], acct[p][j]);
            }
        }
    }
#pragma unroll
    for (int j = 0; j < 4; ++j) {
        const int co = cg * 4 + j;
        float ov[4];
#pragma unroll
        for (int p = 0; p < 4; ++p) {
            float sown = ss[co][p0 + p];
            float beta = 1.f / (1.f + __expf(-acct[p][j]));
            ov[p] = beta * sown + (1.f - beta) * accd[p][j];
        }
        float4 o = {ov[0], ov[1], ov[2], ov[3]};
        *(float4*)(hb + (long)co * HW + px0 + p0) = o;
    }
}

// ---------------- decode 1x1 -> fp32 output ----------------
__global__ __launch_bounds__(256) void dec_k(const float* __restrict__ st,
                                             const float* __restrict__ dT,
                                             const float* __restrict__ db,
                                             float* __restrict__ out) {
    int gid = blockIdx.x * 256 + threadIdx.x;
    long px0 = (long)gid * 2;
    float acc[11][2];
#pragma unroll
    for (int co = 0; co < 11; ++co) {
        float b = db[co];
        acc[co][0] = b;
        acc[co][1] = b;
    }
    for (int ci = 0; ci < 32; ++ci) {
        float2 s2 = *(const float2*)(st + (long)ci * HW + px0);
        const float* wp = dT + ci * 12;
        float4 w0 = *(const float4*)wp, w1 = *(const float4*)(wp + 4), w2 = *(const float4*)(wp + 8);
        float wv[12] = {w0.x, w0.y, w0.z, w0.w, w1.x, w1.y, w1.z, w1.w, w2.x, w2.y, w2.z, w2.w};
#pragma unroll
        for (int co = 0; co < 11; ++co) {
            acc[co][0] = fmaf(s2.x, wv[co], acc[co][0]);
            acc[co][1] = fmaf(s2.y, wv[co], acc[co][1]);
        }
    }
#pragma unroll
    for (int co = 0; co < 11; ++co) {
        float2 o = {acc[co][0], acc[co][1]};
        *(float2*)(out + (long)co * HW + px0) = o;
    }
}

extern "C" void kernel_launch(void* const* d_in, const int* in_sizes, int n_in,
                              void* d_out, int out_size, void* d_ws, size_t ws_size,
                              hipStream_t stream) {
    float* out = (float*)d_out;
    const float* demo_in = (const float*)d_in[0];
    const float* demo_out = (const float*)d_in[1];
    const float* test_in = (const float*)d_in[2];
    const float* enc_w1 = (const float*)d_in[3];
    const float* enc_b1 = (const float*)d_in[4];
    const float* enc_w2 = (const float*)d_in[5];
    const float* enc_b2 = (const float*)d_in[6];
    const float* enc_w3 = (const float*)d_in[7];
    const float* enc_b3 = (const float*)d_in[8];
    const float* enc_lw = (const float*)d_in[9];
    const float* enc_lb = (const float*)d_in[10];
    const float* stem_w = (const float*)d_in[11];
    const float* stem_b = (const float*)d_in[12];
    const float* upd_w1 = (const float*)d_in[13];
    const float* upd_b1 = (const float*)d_in[14];
    const float* upd_w2 = (const float*)d_in[15];
    const float* upd_b2 = (const float*)d_in[16];
    const float* tau_w = (const float*)d_in[17];
    const float* tau_b = (const float*)d_in[18];
    const float* dec_w = (const float*)d_in[19];
    const float* dec_b = (const float*)d_in[20];

    // ---- workspace layout (floats) ----
    float* Wb = (float*)d_ws;
    float* wT_D = Wb + 0;        // 3744 (stem fp32)
    float* w2T  = Wb + 3744;     // 1024
    float* tauT = Wb + 4768;     // 1024
    float* decT = Wb + 5792;     // 384
    float* tauc = Wb + 6176;     // 32
    float* wsum = Wb + 6208;     // 288
    float* means = Wb + 6496;    // 256
    float* bias2 = Wb + 6752;    // 32
    unsigned short* wB1 = (unsigned short*)(Wb + 6784);   // 9*32*32 bf16 (4608 f)
    unsigned short* wB2 = (unsigned short*)(Wb + 11392);  // 9*64*32 (9216 f)
    unsigned short* wB3 = (unsigned short*)(Wb + 20608);  // 9*64*64 (18432 f)
    unsigned short* wBE = (unsigned short*)(Wb + 39040);  // 9*32*32 (4608 f)
    float* big = Wb + 45056;

    const long PD = 7667712;  // per-demo floats (enc1+enc2+enc3)
    const long E1 = 4718592, E2 = 2359296;
    size_t wsf = ws_size / 4;
    int NZ = 1;
    if (wsf >= 45056 + 4 * (size_t)PD) NZ = 4;
    else if (wsf >= 45056 + 2 * (size_t)PD) NZ = 2;

    // ---- fp32 weight transposes (stem + 1x1s + dec) ----
    TJobs J;
    {
        const float* srcs[5] = {stem_w, upd_w2, tau_w, dec_w, dec_w};
        float* dsts[5] = {wT_D, w2T, tauT, decT, decT};
        int couts[5] = {32, 32, 32, 11, 0};
        int cintots[5] = {13, 32, 96, 32, 32};
        int ks[5] = {9, 1, 1, 1, 1};
        int cinsels[5] = {13, 32, 32, 32, 0};
        int coutps[5] = {32, 32, 32, 12, 12};
        int acc0 = 0;
        for (int j = 0; j < 5; ++j) {
            J.src[j] = srcs[j]; J.dst[j] = dsts[j];
            J.cout[j] = couts[j]; J.cintot[j] = cintots[j];
            J.k[j] = ks[j]; J.coutp[j] = coutps[j];
            J.start[j] = acc0;
            acc0 += cinsels[j] * ks[j] * coutps[j];
        }
        J.start[5] = acc0;
        transpose_all_k<<<(acc0 + 255) / 256, 256, 0, stream>>>(J);
    }
    // ---- bf16 MFMA weights (encoder convs + nca 3x3 state part) ----
    WJobs W;
    {
        const float* srcs[4] = {enc_w1, enc_w2, enc_w3, upd_w1};
        unsigned short* dsts[4] = {wB1, wB2, wB3, wBE};
        int couts[4] = {32, 64, 64, 32};
        int cins[4] = {26, 32, 64, 32};
        int cintots[4] = {26, 32, 64, 96};
        int cinps[4] = {32, 32, 64, 32};
        int acc0 = 0;
        for (int j = 0; j < 4; ++j) {
            W.src[j] = srcs[j]; W.dst[j] = dsts[j];
            W.cout[j] = couts[j]; W.cin[j] = cins[j];
            W.cintot[j] = cintots[j]; W.cinp[j] = cinps[j];
            W.start[j] = acc0;
            acc0 += 9 * couts[j] * cinps[j];
        }
        W.start[4] = acc0;
        transpose_wbf_k<<<(acc0 + 255) / 256, 256, 0, stream>>>(W);
    }

    // ---- encoder (bf16 MFMA), NZ demos per launch ----
    for (int d0 = 0; d0 < 4; d0 += NZ) {
        mfma_conv_k<26, 40, 32, 1, 64, 4, 5, true><<<dim3(6, 96, NZ), 256, 0, stream>>>(
            demo_in, demo_out, 13, (long)d0 * 13 * HW, (long)d0 * 13 * HW,
            13L * HW, 13L * HW, 384, 384, wB1, enc_b1, big, PD);
        mfma_conv_k<32, 40, 64, 2, 32, 2, 5, true><<<dim3(6, 96, NZ), 256, 0, stream>>>(
            big, big, 32, 0, 0, PD, PD, 384, 384, wB2, enc_b2, big + E1, PD);
        mfma_conv_k<64, 72, 64, 2, 16, 2, 5, true><<<dim3(6, 48, NZ), 256, 0, stream>>>(
            big + E1, big + E1, 64, 0, 0, PD, PD, 192, 192, wB3, enc_b3,
            big + E1 + E2, PD);
        pool_k<<<64 * NZ, 256, 0, stream>>>(big + E1 + E2, PD, means + d0 * 64);
    }
    prep_te_k<<<1, 256, 0, stream>>>(means, enc_lw, enc_lb, tau_w, tau_b, upd_w1,
                                     upd_b1, tauc, wsum, bias2);

    // ---- stem (fp32 exact) -> sA ----
    float* sA = big;
    float* sX = big + E1;
    conv3x3_k<13, 13, 13, 32, 1, 32, 8, 5><<<dim3(12, 48, 1), 256, 0, stream>>>(
        test_in, test_in, 13, 0, 0, 0, 0, 384, 384, wT_D, stem_b, sA, 0);

    // ---- 8 NCA steps: A) mfma 3x3 -> h1_raw(b)   B) fused 1x1s+gate (b in place)
    float* a = sA;
    float* b = sX;
    for (int s = 0; s < 8; ++s) {
        mfma_conv_k<32, 40, 32, 1, 32, 8, 5, false><<<dim3(12, 48, 1), 256, 0, stream>>>(
            a, a, 32, 0, 0, 0, 0, 384, 384, wBE, bias2, b, 0);
        nca_fuse_k<<<1152, 256, 0, stream>>>(a, b, wsum, w2T, upd_b2, tauT, tauc);
        float* t = a; a = b; b = t;
    }
    dec_k<<<288, 256, 0, stream>>>(a, decT, dec_b, out);
}

// Round 22
// 490.252 us; speedup vs baseline: 12.7025x; 1.0288x over previous
//
#include <hip/hip_runtime.h>

#define HW 147456  // 384*384

typedef __attribute__((ext_vector_type(8))) short bf16x8;
typedef __attribute__((ext_vector_type(4))) float f32x4;

__device__ __forceinline__ float bf2f(unsigned short u) {
    return __uint_as_float(((unsigned)u) << 16);
}
__device__ __forceinline__ unsigned short f2bf(float f) {
    unsigned u = __float_as_uint(f);
    return (unsigned short)((u + 0x7fffu + ((u >> 16) & 1u)) >> 16);  // RNE
}

// ---------------- fp32 weight transpose: w[COUT][CINTOT][K] -> wT[cin][k][COUTP] ----------------
struct TJobs {
    const float* src[5];
    float* dst[5];
    int cout[5], cintot[5], k[5], coutp[5];
    int start[6];
};

__global__ __launch_bounds__(256) void transpose_all_k(TJobs J) {
    int gid = blockIdx.x * 256 + threadIdx.x;
    if (gid >= J.start[5]) return;
    int j = 0;
#pragma unroll
    for (int t = 1; t < 5; ++t)
        if (gid >= J.start[t]) j = t;
    int li = gid - J.start[j];
    int coutp = J.coutp[j], K = J.k[j];
    int co = li % coutp;
    int kk = (li / coutp) % K;
    int cin = li / (coutp * K);
    J.dst[j][li] = (co < J.cout[j]) ? J.src[j][((co * J.cintot[j]) + cin) * K + kk] : 0.f;
}

// ---------------- bf16 weight prep for MFMA: w[COUT][CINTOT][9] -> wB[9][COUT][CINP] ----------------
struct WJobs {
    const float* src[4];
    unsigned short* dst[4];
    int cout[4], cin[4], cintot[4], cinp[4];
    int start[5];
};

__global__ __launch_bounds__(256) void transpose_wbf_k(WJobs J) {
    int gid = blockIdx.x * 256 + threadIdx.x;
    if (gid >= J.start[4]) return;
    int j = 0;
#pragma unroll
    for (int t = 1; t < 4; ++t)
        if (gid >= J.start[t]) j = t;
    int li = gid - J.start[j];
    int cinp = J.cinp[j];
    int ci = li % cinp;
    int co = (li / cinp) % J.cout[j];
    int tap = li / (cinp * J.cout[j]);
    float v = (ci < J.cin[j]) ? J.src[j][((co * J.cintot[j]) + ci) * 9 + tap] : 0.f;
    J.dst[j][li] = f2bf(v);
}

// ---------------- bf16 MFMA implicit-GEMM 3x3 conv (encoder), pad=1, ReLU ----------------
template <int CIN, int CP, int COUT, int S, int OX, int OY, int MW, bool RELU>
__global__ __launch_bounds__(256, MW) void mfma_conv_k(
    const float* __restrict__ in0, const float* __restrict__ in1, int split,
    long off0base, long off1base, long zs0, long zs1, int inW, int inH,
    const unsigned short* __restrict__ wB,  // [9][COUT][CINK] bf16
    const float* __restrict__ bias,
    float* __restrict__ out, long outZS) {
    constexpr int XT = (OX - 1) * S + 3;
    constexpr int YT = (OY - 1) * S + 3;
    constexpr int CINK = (CIN + 31) & ~31;
    constexpr int KST = CINK / 32;
    constexpr int NCG = COUT / 16;
    constexpr int NTX = OX / 16;
    constexpr int NSP = NTX * OY;
    constexpr int NTASK = NSP * NCG;
    constexpr int NT4 = NTASK / 4;
    constexpr int NSLOT = YT * XT;
    static_assert(NTASK % 4 == 0, "tasks per wave");
    static_assert(NSP % NT4 == 0, "wave must own a single cout-group");
    static_assert(CP % 8 == 0 && CP >= CINK, "LDS cin pad");
    static_assert((CP / 8) % 2 == 1, "odd chunk stride for bank spread");
    __shared__ __align__(16) unsigned short tile[NSLOT * CP];
    const int tid = threadIdx.x;
    const int bx = blockIdx.x, by = blockIdx.y, z = blockIdx.z;
    const long o0 = off0base + (long)z * zs0;
    const long o1 = off1base + (long)z * zs1;
    const int outW = inW / S, outH = inH / S;
    const int gx0 = bx * OX * S - 1;
    const int gy0 = by * OY * S - 1;

#pragma unroll 1
    for (int s = tid; s < NSLOT; s += 256) {
        const int sy = s / XT;
        const int lx = s - sy * XT;
        const int gy = gy0 + sy;
        const int gx = gx0 + lx;
        const bool ok = ((unsigned)gy < (unsigned)inH) && ((unsigned)gx < (unsigned)inW);
        const long pix = (long)gy * inW + gx;
#pragma unroll
        for (int h = 0; h < CINK / 8; ++h) {
            bf16x8 v;
#pragma unroll
            for (int e = 0; e < 8; ++e) {
                const int c = h * 8 + e;
                float f = 0.f;
                if (c < CIN && ok) {
                    const float* base = (c < split)
                        ? in0 + o0 + (long)c * inH * inW
                        : in1 + o1 + (long)(c - split) * inH * inW;
                    f = base[pix];
                }
                v[e] = (short)f2bf(f);
            }
            *(bf16x8*)(tile + s * CP + h * 8) = v;
        }
    }
    __syncthreads();

    const int wv = tid >> 6;
    const int l = tid & 63;
    const int ln = l & 15;
    const int lk = l >> 4;
    const int cg = (wv * NT4) / NSP;
    bf16x8 bfr[9 * KST];
#pragma unroll
    for (int tap = 0; tap < 9; ++tap)
#pragma unroll
        for (int h = 0; h < KST; ++h)
            bfr[tap * KST + h] = *(const bf16x8*)(wB + ((long)(tap * COUT + cg * 16 + ln)) * CINK + h * 32 + lk * 8);
    const float bv = bias[cg * 16 + ln];
#pragma unroll 1
    for (int t = 0; t < NT4; ++t) {
        const int sp = wv * NT4 + t - cg * NSP;
        const int tx = sp % NTX;
        const int ty = sp / NTX;
        f32x4 acc;
        acc[0] = bv; acc[1] = bv; acc[2] = bv; acc[3] = bv;
#pragma unroll
        for (int ky = 0; ky < 3; ++ky) {
#pragma unroll
            for (int kx = 0; kx < 3; ++kx) {
                const int yb = ty * S + ky;
                const int xb = (tx * 16 + ln) * S + kx;
                const unsigned short* ap = tile + (yb * XT + xb) * CP + lk * 8;
#pragma unroll
                for (int h = 0; h < KST; ++h) {
                    bf16x8 a = *(const bf16x8*)(ap + h * 32);
                    acc = __builtin_amdgcn_mfma_f32_16x16x32_bf16(a, bfr[(ky * 3 + kx) * KST + h], acc, 0, 0, 0);
                }
            }
        }
        const int ox = bx * OX + tx * 16 + lk * 4;
        const int oy = by * OY + ty;
        float4 o;
        if constexpr (RELU) {
            o.x = fmaxf(acc[0], 0.f);
            o.y = fmaxf(acc[1], 0.f);
            o.z = fmaxf(acc[2], 0.f);
            o.w = fmaxf(acc[3], 0.f);
        } else {
            o.x = acc[0]; o.y = acc[1]; o.z = acc[2]; o.w = acc[3];
        }
        *(float4*)(out + (long)z * outZS + ((long)(cg * 16 + ln) * outH + oy) * outW + ox) = o;
    }
}

// ---------------- fp32 LDS-tiled 3x3 conv (stem only: precision-critical) ----------------
template <int CIN, int CCHUNK, int WCH, int COUT, int STRIDE, int TW, int CO_PER, int MW>
__global__ __launch_bounds__(256, MW) void conv3x3_k(
    const float* __restrict__ in0, const float* __restrict__ in1, int split,
    long inOff0, long inOff1, long zs0, long zs1, int inW, int inH,
    const float* __restrict__ wT, const float* __restrict__ bias,
    float* __restrict__ out, long outZS) {
    constexpr int NCG = COUT / CO_PER;
    constexpr int NPXG = 256 / NCG;
    constexpr int NXG = TW / 4;
    constexpr int TH = NPXG / NXG;
    constexpr int INW = (TW - 1) * STRIDE + 3;
    constexpr int INH = (TH - 1) * STRIDE + 3;
    constexpr int WIN = 3 * STRIDE + 3;
    constexpr int XV = (INW + 6) / 4;
    constexpr int LDSW = XV * 4 + 1;
    constexpr int SLOTS = INH * XV;
    static_assert(NPXG % NXG == 0 && NPXG * NCG == 256, "thread mapping");
    static_assert(CIN % CCHUNK == 0 && CCHUNK % WCH == 0, "chunking");
    static_assert(SLOTS <= 256, "staging slots");
    __shared__ float tile[CCHUNK][INH][LDSW];
    __shared__ __align__(16) float wlds[WCH * 9 * COUT];
    const int tid = threadIdx.x;
    const int cg = tid / NPXG;
    const int pg = tid % NPXG;
    const int xg = pg % NXG;
    const int yy = pg / NXG;
    const int bx = blockIdx.x, by = blockIdx.y, z = blockIdx.z;
    const int outW = inW / STRIDE, outH = inH / STRIDE;
    const long off0 = inOff0 + (long)z * zs0;
    const long off1 = inOff1 + (long)z * zs1;
    float* outp = out + (long)z * outZS;
    const bool sact = tid < SLOTS;
    const int sr = tid / XV;
    const int sx = tid - sr * XV;
    const int gxs = bx * TW * STRIDE - 4 + sx * 4;
    const int gy0 = by * TH * STRIDE - 1;

    float acc[4][CO_PER];
    {
        float bv[CO_PER];
#pragma unroll
        for (int jj = 0; jj < CO_PER; jj += 4) {
            float4 b4 = *(const float4*)(bias + cg * CO_PER + jj);
            bv[jj] = b4.x; bv[jj + 1] = b4.y; bv[jj + 2] = b4.z; bv[jj + 3] = b4.w;
        }
#pragma unroll
        for (int p = 0; p < 4; ++p)
#pragma unroll
            for (int j = 0; j < CO_PER; ++j) acc[p][j] = bv[j];
    }

    for (int ch = 0; ch < CIN; ch += CCHUNK) {
        if (sact) {
            const int gy = gy0 + sr;
            const bool yok = (unsigned)gy < (unsigned)inH;
            const bool xfull = (gxs >= 0) && (gxs + 3 < inW);
#pragma unroll
            for (int c = 0; c < CCHUNK; ++c) {
                const int gc = ch + c;
                const float* row = (gc < split)
                    ? in0 + off0 + ((long)gc * inH + gy) * inW
                    : in1 + off1 + ((long)(gc - split) * inH + gy) * inW;
                float4 v = {0.f, 0.f, 0.f, 0.f};
                if (yok) {
                    if (xfull) {
                        v = *(const float4*)(row + gxs);
                    } else {
                        float t[4];
#pragma unroll
                        for (int k = 0; k < 4; ++k) {
                            int gx = gxs + k;
                            t[k] = ((unsigned)gx < (unsigned)inW) ? row[gx] : 0.f;
                        }
                        v = {t[0], t[1], t[2], t[3]};
                    }
                }
                float* dst = &tile[c][sr][sx * 4];
                dst[0] = v.x; dst[1] = v.y; dst[2] = v.z; dst[3] = v.w;
            }
        }
#pragma unroll 1
        for (int wc = 0; wc < CCHUNK; wc += WCH) {
            {
                const float4* wsrc = (const float4*)(wT + (long)(ch + wc) * 9 * COUT);
                float4* wdst = (float4*)wlds;
                constexpr int CNT = WCH * 9 * COUT / 4;
                for (int i = tid; i < CNT; i += 256) wdst[i] = wsrc[i];
            }
            __syncthreads();
#pragma unroll 1
            for (int c = 0; c < WCH; ++c) {
#pragma unroll
                for (int ky = 0; ky < 3; ++ky) {
                    const int ty = yy * STRIDE + ky;
                    const int tx0 = xg * 4 * STRIDE + 3;
                    float xw[WIN];
#pragma unroll
                    for (int i = 0; i < WIN; ++i) xw[i] = tile[wc + c][ty][tx0 + i];
#pragma unroll
                    for (int dx = 0; dx < 3; ++dx) {
                        const float* wp = wlds + ((c * 3 + ky) * 3 + dx) * COUT + cg * CO_PER;
                        float wv[CO_PER];
#pragma unroll
                        for (int jj = 0; jj < CO_PER; jj += 4) {
                            float4 w4 = *(const float4*)(wp + jj);
                            wv[jj] = w4.x; wv[jj + 1] = w4.y; wv[jj + 2] = w4.z; wv[jj + 3] = w4.w;
                        }
#pragma unroll
                        for (int p = 0; p < 4; ++p) {
                            float xv = xw[p * STRIDE + dx];
#pragma unroll
                            for (int j = 0; j < CO_PER; ++j) acc[p][j] = fmaf(xv, wv[j], acc[p][j]);
                        }
                    }
                }
            }
            __syncthreads();
        }
    }

    const int ox0 = bx * TW + xg * 4;
    const int oy = by * TH + yy;
#pragma unroll
    for (int j = 0; j < CO_PER; ++j) {
        int co = cg * CO_PER + j;
        float4 o;
        o.x = fmaxf(acc[0][j], 0.f);
        o.y = fmaxf(acc[1][j], 0.f);
        o.z = fmaxf(acc[2][j], 0.f);
        o.w = fmaxf(acc[3][j], 0.f);
        *(float4*)(outp + ((long)co * outH + oy) * outW + ox0) = o;
    }
}

// ---------------- spatial mean over 96x96 plane, z-batched ----------------
__global__ __launch_bounds__(256) void pool_k(const float* __restrict__ enc3base,
                                              long zstride,
                                              float* __restrict__ meanout) {
    int z = blockIdx.x >> 6;
    int c = blockIdx.x & 63;
    const float* p = enc3base + (long)z * zstride + (long)c * 9216;
    float s = 0.f;
    for (int i = threadIdx.x; i < 9216; i += 256) s += p[i];
    __shared__ float red[256];
    red[threadIdx.x] = s;
    __syncthreads();
    for (int o = 128; o > 0; o >>= 1) {
        if (threadIdx.x < o) red[threadIdx.x] += red[threadIdx.x + o];
        __syncthreads();
    }
    if (threadIdx.x == 0) meanout[z * 64 + c] = red[0] * (1.f / 9216.f);
}

// ---------------- task embedding + te-derived constants ----------------
__global__ __launch_bounds__(256) void prep_te_k(
    const float* __restrict__ means, const float* __restrict__ lw,
    const float* __restrict__ lb, const float* __restrict__ tauw,
    const float* __restrict__ taub, const float* __restrict__ w1,
    const float* __restrict__ b1,
    float* __restrict__ tauc, float* __restrict__ wsum,
    float* __restrict__ bias2) {
    __shared__ float tes[64];
    int t = threadIdx.x;
    if (t < 64) {
        float s = 0.f;
        for (int d = 0; d < 4; ++d)
            for (int c = 0; c < 64; ++c) s += means[d * 64 + c] * lw[t * 64 + c];
        tes[t] = lb[t] + 0.25f * s;
    }
    __syncthreads();
    if (t < 32) {
        float s = taub[t];
        for (int e = 0; e < 64; ++e) s += tauw[t * 96 + 32 + e] * tes[e];
        tauc[t] = s;
    }
    for (int i = t; i < 288; i += 256) {
        int co = i % 32;
        int k = i / 32;
        float s = 0.f;
        for (int e = 0; e < 64; ++e) s += w1[((co * 96) + 32 + e) * 9 + k] * tes[e];
        wsum[i] = s;
    }
    __syncthreads();
    if (t < 32) {
        float s = b1[t];
        for (int k = 0; k < 9; ++k) s += wsum[k * 32 + t];
        bias2[t] = s;  // b1 + full 9-tap te sum (border fixed in fused step)
    }
}

// ---------------- FUSED NCA step: mfma 3x3 + border-corr/relu + 1x1s + gate ----------------
// Block = 32x4 output px, all 32 couts. Phase 1: stage s_old (bf16 tile for
// MFMA + fp32 centers for the gate, same pass). Phase 2: R21's proven mfma
// conv (16 tasks, 4/wave, D-frags in 16 statically-indexed VGPRs). Phase 3:
// border-corr + relu + bf16 h into the dead tile LDS region. Phase 4: R21's
// proven fuse shape (8cg x 32pg, accd[4][4]+acct[4][4]) writing s_new to the
// ping-pong buffer. Kills the 37.8 MB/step h1_raw HBM round-trip.
__global__ __launch_bounds__(256, 2) void nca_step_fused_k(
    const float* __restrict__ sold, float* __restrict__ snew,
    const unsigned short* __restrict__ wBE,  // [9][32][32] bf16
    const float* __restrict__ bias2,
    const float* __restrict__ wsum,
    const float* __restrict__ w2T, const float* __restrict__ b2,
    const float* __restrict__ tauT, const float* __restrict__ tauc) {
    // XT=34, YT=6, NSLOT=204, CP=40
    __shared__ __align__(16) unsigned short tile[204 * 40];  // 16,320 B; h1s[32][136] after conv
    __shared__ __align__(16) float ss[32][132];              // 16,896 B (fp32 centers)
    __shared__ __align__(16) float sw2[1024], stu[1024];     //  8,192 B
    __shared__ float sb2[32], stc[32];
    const int tid = threadIdx.x;
    const int bx = blockIdx.x, by = blockIdx.y;
    const int gx0 = bx * 32 - 1;
    const int gy0 = by * 4 - 1;

    for (int i = tid; i < 1024; i += 256) {
        sw2[i] = w2T[i];
        stu[i] = tauT[i];
    }
    if (tid < 32) {
        sb2[tid] = b2[tid];
        stc[tid] = tauc[tid];
    }
    // ---- phase 1: stage tile (bf16) + centers (fp32) ----
    if (tid < 204) {
        const int sy = tid / 34;
        const int lx = tid - sy * 34;
        const int gy = gy0 + sy;
        const int gx = gx0 + lx;
        const bool ok = ((unsigned)gy < 384u) && ((unsigned)gx < 384u);
        const long pix = (long)gy * 384 + gx;
        const bool ctr = (sy >= 1) && (sy <= 4) && (lx >= 1) && (lx <= 32);
        const int pxl = (sy - 1) * 32 + (lx - 1);
#pragma unroll
        for (int h = 0; h < 4; ++h) {
            bf16x8 v;
#pragma unroll
            for (int e = 0; e < 8; ++e) {
                const int c = h * 8 + e;
                float f = ok ? sold[(long)c * HW + pix] : 0.f;
                v[e] = (short)f2bf(f);
                if (ctr) ss[c][pxl] = f;
            }
            *(bf16x8*)(tile + tid * 40 + h * 8) = v;
        }
    }
    __syncthreads();

    // ---- phase 2: mfma conv, 16 tasks (4/wave), results in registers ----
    const int wv = tid >> 6;
    const int l = tid & 63;
    const int ln = l & 15;
    const int lk = l >> 4;
    const int cg = wv >> 1;  // waves 0,1 -> couts 0-15; waves 2,3 -> 16-31
    const int co = cg * 16 + ln;
    bf16x8 bfr[9];
#pragma unroll
    for (int tap = 0; tap < 9; ++tap)
        bfr[tap] = *(const bf16x8*)(wBE + ((long)(tap * 32 + co)) * 32 + lk * 8);
    const float bv = bias2[co];
    f32x4 accs[4];
#pragma unroll
    for (int t = 0; t < 4; ++t) {
        const int sp = (wv & 1) * 4 + t;
        const int tx = sp & 1;
        const int ty = sp >> 1;
        f32x4 acc;
        acc[0] = bv; acc[1] = bv; acc[2] = bv; acc[3] = bv;
#pragma unroll
        for (int ky = 0; ky < 3; ++ky) {
#pragma unroll
            for (int kx = 0; kx < 3; ++kx) {
                const unsigned short* ap = tile + ((ty + ky) * 34 + tx * 16 + ln + kx) * 40 + lk * 8;
                bf16x8 a = *(const bf16x8*)ap;
                acc = __builtin_amdgcn_mfma_f32_16x16x32_bf16(a, bfr[ky * 3 + kx], acc, 0, 0, 0);
            }
        }
        accs[t] = acc;
    }
    __syncthreads();  // all tile reads done -> safe to overwrite with h

    // ---- phase 3: border-corr + relu + bf16 h into tile region ----
    unsigned short (*h1s)[136] = (unsigned short(*)[136])tile;
#pragma unroll
    for (int t = 0; t < 4; ++t) {
        const int sp = (wv & 1) * 4 + t;
        const int tx = sp & 1;
        const int ty = sp >> 1;
        const int gy = by * 4 + ty;
        const int gxb = bx * 32 + tx * 16 + lk * 4;
        float hv[4] = {accs[t][0], accs[t][1], accs[t][2], accs[t][3]};
        const bool ytop = (gy == 0), ybot = (gy == 383);
#pragma unroll
        for (int r = 0; r < 4; ++r) {
            const int gx = gxb + r;
            const bool xl = (gx == 0), xr = (gx == 383);
            if (xl | xr | ytop | ybot) {
                float h = hv[r];
#pragma unroll
                for (int ky = 0; ky < 3; ++ky)
#pragma unroll
                    for (int kx = 0; kx < 3; ++kx) {
                        bool inval = (ky == 0 && ytop) || (ky == 2 && ybot) ||
                                     (kx == 0 && xl) || (kx == 2 && xr);
                        if (inval) h -= wsum[(ky * 3 + kx) * 32 + co];
                    }
                hv[r] = h;
            }
        }
        ushort4 ho;
        ho.x = f2bf(fmaxf(hv[0], 0.f));
        ho.y = f2bf(fmaxf(hv[1], 0.f));
        ho.z = f2bf(fmaxf(hv[2], 0.f));
        ho.w = f2bf(fmaxf(hv[3], 0.f));
        *(ushort4*)(&h1s[co][ty * 32 + tx * 16 + lk * 4]) = ho;
    }
    __syncthreads();

    // ---- phase 4: fused 1x1s + gate (R21 proven shape) ----
    const int cg2 = tid >> 5;  // 8 groups x 4 couts
    const int pg = tid & 31;   // 32 x 4 px
    const int p0 = pg * 4;
    float accd[4][4], acct[4][4];
    {
        float dv[4], tv[4];
#pragma unroll
        for (int j = 0; j < 4; ++j) {
            dv[j] = sb2[cg2 * 4 + j];
            tv[j] = stc[cg2 * 4 + j];
        }
#pragma unroll
        for (int p = 0; p < 4; ++p)
#pragma unroll
            for (int j = 0; j < 4; ++j) { accd[p][j] = dv[j]; acct[p][j] = tv[j]; }
    }
#pragma unroll 2
    for (int ci = 0; ci < 32; ++ci) {
        float hv[4], sv[4];
#pragma unroll
        for (int p = 0; p < 4; ++p) {
            hv[p] = bf2f(h1s[ci][p0 + p]);
            sv[p] = ss[ci][p0 + p];
        }
        float4 wd4 = *(const float4*)(sw2 + ci * 32 + cg2 * 4);
        float4 wt4 = *(const float4*)(stu + ci * 32 + cg2 * 4);
        float wdv[4] = {wd4.x, wd4.y, wd4.z, wd4.w};
        float wtv[4] = {wt4.x, wt4.y, wt4.z, wt4.w};
#pragma unroll
        for (int p = 0; p < 4; ++p) {
#pragma unroll
            for (int j = 0; j < 4; ++j) {
                accd[p][j] = fmaf(hv[p], wdv[j], accd[p][j]);
                acct[p][j] = fmaf(sv[p], wtv[j], acct[p][j]);
            }
        }
    }
    const int yl = p0 >> 5;
    const int xl2 = p0 & 31;
    const long obase = ((long)(by * 4 + yl)) * 384 + bx * 32 + xl2;
#pragma unroll
    for (int j = 0; j < 4; ++j) {
        const int co2 = cg2 * 4 + j;
        float ov[4];
#pragma unroll
        for (int p = 0; p < 4; ++p) {
            float sown = ss[co2][p0 + p];
            float beta = 1.f / (1.f + __expf(-acct[p][j]));
            ov[p] = beta * sown + (1.f - beta) * accd[p][j];
        }
        float4 o = {ov[0], ov[1], ov[2], ov[3]};
        *(float4*)(snew + (long)co2 * HW + obase) = o;
    }
}

// ---------------- decode 1x1 -> fp32 output ----------------
__global__ __launch_bounds__(256) void dec_k(const float* __restrict__ st,
                                             const float* __restrict__ dT,
                                             const float* __restrict__ db,
                                             float* __restrict__ out) {
    int gid = blockIdx.x * 256 + threadIdx.x;
    long px0 = (long)gid * 2;
    float acc[11][2];
#pragma unroll
    for (int co = 0; co < 11; ++co) {
        float b = db[co];
        acc[co][0] = b;
        acc[co][1] = b;
    }
    for (int ci = 0; ci < 32; ++ci) {
        float2 s2 = *(const float2*)(st + (long)ci * HW + px0);
        const float* wp = dT + ci * 12;
        float4 w0 = *(const float4*)wp, w1 = *(const float4*)(wp + 4), w2 = *(const float4*)(wp + 8);
        float wv[12] = {w0.x, w0.y, w0.z, w0.w, w1.x, w1.y, w1.z, w1.w, w2.x, w2.y, w2.z, w2.w};
#pragma unroll
        for (int co = 0; co < 11; ++co) {
            acc[co][0] = fmaf(s2.x, wv[co], acc[co][0]);
            acc[co][1] = fmaf(s2.y, wv[co], acc[co][1]);
        }
    }
#pragma unroll
    for (int co = 0; co < 11; ++co) {
        float2 o = {acc[co][0], acc[co][1]};
        *(float2*)(out + (long)co * HW + px0) = o;
    }
}

extern "C" void kernel_launch(void* const* d_in, const int* in_sizes, int n_in,
                              void* d_out, int out_size, void* d_ws, size_t ws_size,
                              hipStream_t stream) {
    float* out = (float*)d_out;
    const float* demo_in = (const float*)d_in[0];
    const float* demo_out = (const float*)d_in[1];
    const float* test_in = (const float*)d_in[2];
    const float* enc_w1 = (const float*)d_in[3];
    const float* enc_b1 = (const float*)d_in[4];
    const float* enc_w2 = (const float*)d_in[5];
    const float* enc_b2 = (const float*)d_in[6];
    const float* enc_w3 = (const float*)d_in[7];
    const float* enc_b3 = (const float*)d_in[8];
    const float* enc_lw = (const float*)d_in[9];
    const float* enc_lb = (const float*)d_in[10];
    const float* stem_w = (const float*)d_in[11];
    const float* stem_b = (const float*)d_in[12];
    const float* upd_w1 = (const float*)d_in[13];
    const float* upd_b1 = (const float*)d_in[14];
    const float* upd_w2 = (const float*)d_in[15];
    const float* upd_b2 = (const float*)d_in[16];
    const float* tau_w = (const float*)d_in[17];
    const float* tau_b = (const float*)d_in[18];
    const float* dec_w = (const float*)d_in[19];
    const float* dec_b = (const float*)d_in[20];

    // ---- workspace layout (floats) ----
    float* Wb = (float*)d_ws;
    float* wT_D = Wb + 0;        // 3744 (stem fp32)
    float* w2T  = Wb + 3744;     // 1024
    float* tauT = Wb + 4768;     // 1024
    float* decT = Wb + 5792;     // 384
    float* tauc = Wb + 6176;     // 32
    float* wsum = Wb + 6208;     // 288
    float* means = Wb + 6496;    // 256
    float* bias2 = Wb + 6752;    // 32
    unsigned short* wB1 = (unsigned short*)(Wb + 6784);   // 9*32*32 bf16 (4608 f)
    unsigned short* wB2 = (unsigned short*)(Wb + 11392);  // 9*64*32 (9216 f)
    unsigned short* wB3 = (unsigned short*)(Wb + 20608);  // 9*64*64 (18432 f)
    unsigned short* wBE = (unsigned short*)(Wb + 39040);  // 9*32*32 (4608 f)
    float* big = Wb + 45056;

    const long PD = 7667712;  // per-demo floats (enc1+enc2+enc3)
    const long E1 = 4718592, E2 = 2359296;
    size_t wsf = ws_size / 4;
    int NZ = 1;
    if (wsf >= 45056 + 4 * (size_t)PD) NZ = 4;
    else if (wsf >= 45056 + 2 * (size_t)PD) NZ = 2;

    // ---- fp32 weight transposes (stem + 1x1s + dec) ----
    TJobs J;
    {
        const float* srcs[5] = {stem_w, upd_w2, tau_w, dec_w, dec_w};
        float* dsts[5] = {wT_D, w2T, tauT, decT, decT};
        int couts[5] = {32, 32, 32, 11, 0};
        int cintots[5] = {13, 32, 96, 32, 32};
        int ks[5] = {9, 1, 1, 1, 1};
        int cinsels[5] = {13, 32, 32, 32, 0};
        int coutps[5] = {32, 32, 32, 12, 12};
        int acc0 = 0;
        for (int j = 0; j < 5; ++j) {
            J.src[j] = srcs[j]; J.dst[j] = dsts[j];
            J.cout[j] = couts[j]; J.cintot[j] = cintots[j];
            J.k[j] = ks[j]; J.coutp[j] = coutps[j];
            J.start[j] = acc0;
            acc0 += cinsels[j] * ks[j] * coutps[j];
        }
        J.start[5] = acc0;
        transpose_all_k<<<(acc0 + 255) / 256, 256, 0, stream>>>(J);
    }
    // ---- bf16 MFMA weights (encoder convs + nca 3x3 state part) ----
    WJobs W;
    {
        const float* srcs[4] = {enc_w1, enc_w2, enc_w3, upd_w1};
        unsigned short* dsts[4] = {wB1, wB2, wB3, wBE};
        int couts[4] = {32, 64, 64, 32};
        int cins[4] = {26, 32, 64, 32};
        int cintots[4] = {26, 32, 64, 96};
        int cinps[4] = {32, 32, 64, 32};
        int acc0 = 0;
        for (int j = 0; j < 4; ++j) {
            W.src[j] = srcs[j]; W.dst[j] = dsts[j];
            W.cout[j] = couts[j]; W.cin[j] = cins[j];
            W.cintot[j] = cintots[j]; W.cinp[j] = cinps[j];
            W.start[j] = acc0;
            acc0 += 9 * couts[j] * cinps[j];
        }
        W.start[4] = acc0;
        transpose_wbf_k<<<(acc0 + 255) / 256, 256, 0, stream>>>(W);
    }

    // ---- encoder (bf16 MFMA), NZ demos per launch ----
    for (int d0 = 0; d0 < 4; d0 += NZ) {
        mfma_conv_k<26, 40, 32, 1, 64, 4, 5, true><<<dim3(6, 96, NZ), 256, 0, stream>>>(
            demo_in, demo_out, 13, (long)d0 * 13 * HW, (long)d0 * 13 * HW,
            13L * HW, 13L * HW, 384, 384, wB1, enc_b1, big, PD);
        mfma_conv_k<32, 40, 64, 2, 32, 2, 5, true><<<dim3(6, 96, NZ), 256, 0, stream>>>(
            big, big, 32, 0, 0, PD, PD, 384, 384, wB2, enc_b2, big + E1, PD);
        mfma_conv_k<64, 72, 64, 2, 16, 2, 5, true><<<dim3(6, 48, NZ), 256, 0, stream>>>(
            big + E1, big + E1, 64, 0, 0, PD, PD, 192, 192, wB3, enc_b3,
            big + E1 + E2, PD);
        pool_k<<<64 * NZ, 256, 0, stream>>>(big + E1 + E2, PD, means + d0 * 64);
    }
    prep_te_k<<<1, 256, 0, stream>>>(means, enc_lw, enc_lb, tau_w, tau_b, upd_w1,
                                     upd_b1, tauc, wsum, bias2);

    // ---- stem (fp32 exact) -> sA ----
    float* sA = big;
    float* sX = big + E1;
    conv3x3_k<13, 13, 13, 32, 1, 32, 8, 5><<<dim3(12, 48, 1), 256, 0, stream>>>(
        test_in, test_in, 13, 0, 0, 0, 0, 384, 384, wT_D, stem_b, sA, 0);

    // ---- 8 fused NCA steps (n_steps==8 per setup_inputs), ping-pong ----
    float* a = sA;
    float* b = sX;
    for (int s = 0; s < 8; ++s) {
        nca_step_fused_k<<<dim3(12, 96), 256, 0, stream>>>(
            a, b, wBE, bias2, wsum, w2T, upd_b2, tauT, tauc);
        float* t = a; a = b; b = t;
    }
    dec_k<<<288, 256, 0, stream>>>(a, decT, dec_b, out);
}

// Round 23
// 481.266 us; speedup vs baseline: 12.9397x; 1.0187x over previous
//
#include <hip/hip_runtime.h>

#define HW 147456  // 384*384

typedef __attribute__((ext_vector_type(8))) short bf16x8;
typedef __attribute__((ext_vector_type(4))) float f32x4;

__device__ __forceinline__ float bf2f(unsigned short u) {
    return __uint_as_float(((unsigned)u) << 16);
}
__device__ __forceinline__ unsigned short f2bf(float f) {
    unsigned u = __float_as_uint(f);
    return (unsigned short)((u + 0x7fffu + ((u >> 16) & 1u)) >> 16);  // RNE
}

// ---------------- fp32 weight transpose: w[COUT][CINTOT][K] -> wT[cin][k][COUTP] ----------------
struct TJobs {
    const float* src[5];
    float* dst[5];
    int cout[5], cintot[5], k[5], coutp[5];
    int start[6];
};

__global__ __launch_bounds__(256) void transpose_all_k(TJobs J) {
    int gid = blockIdx.x * 256 + threadIdx.x;
    if (gid >= J.start[5]) return;
    int j = 0;
#pragma unroll
    for (int t = 1; t < 5; ++t)
        if (gid >= J.start[t]) j = t;
    int li = gid - J.start[j];
    int coutp = J.coutp[j], K = J.k[j];
    int co = li % coutp;
    int kk = (li / coutp) % K;
    int cin = li / (coutp * K);
    J.dst[j][li] = (co < J.cout[j]) ? J.src[j][((co * J.cintot[j]) + cin) * K + kk] : 0.f;
}

// ---------------- bf16 weight prep for MFMA: w[COUT][CINTOT][9] -> wB[9][COUT][CINP] ----------------
struct WJobs {
    const float* src[4];
    unsigned short* dst[4];
    int cout[4], cin[4], cintot[4], cinp[4];
    int start[5];
};

__global__ __launch_bounds__(256) void transpose_wbf_k(WJobs J) {
    int gid = blockIdx.x * 256 + threadIdx.x;
    if (gid >= J.start[4]) return;
    int j = 0;
#pragma unroll
    for (int t = 1; t < 4; ++t)
        if (gid >= J.start[t]) j = t;
    int li = gid - J.start[j];
    int cinp = J.cinp[j];
    int ci = li % cinp;
    int co = (li / cinp) % J.cout[j];
    int tap = li / (cinp * J.cout[j]);
    float v = (ci < J.cin[j]) ? J.src[j][((co * J.cintot[j]) + ci) * 9 + tap] : 0.f;
    J.dst[j][li] = f2bf(v);
}

// ---------------- bf16 MFMA implicit-GEMM 3x3 conv (encoder), pad=1, ReLU ----------------
// INBF: input buffer already bf16 (raw copy into LDS -> bitwise identical to
// staging f2bf(fp32)). OUTBF: store f2bf(result) (consumer stages bf16 anyway).
template <int CIN, int CP, int COUT, int S, int OX, int OY, int MW, bool RELU,
          bool INBF, bool OUTBF>
__global__ __launch_bounds__(256, MW) void mfma_conv_k(
    const void* __restrict__ vin0, const void* __restrict__ vin1, int split,
    long off0base, long off1base, long zs0, long zs1, int inW, int inH,
    const unsigned short* __restrict__ wB,  // [9][COUT][CINK] bf16
    const float* __restrict__ bias,
    void* __restrict__ vout, long outZS) {
    constexpr int XT = (OX - 1) * S + 3;
    constexpr int YT = (OY - 1) * S + 3;
    constexpr int CINK = (CIN + 31) & ~31;
    constexpr int KST = CINK / 32;
    constexpr int NCG = COUT / 16;
    constexpr int NTX = OX / 16;
    constexpr int NSP = NTX * OY;
    constexpr int NTASK = NSP * NCG;
    constexpr int NT4 = NTASK / 4;
    constexpr int NSLOT = YT * XT;
    static_assert(NTASK % 4 == 0, "tasks per wave");
    static_assert(NSP % NT4 == 0, "wave must own a single cout-group");
    static_assert(CP % 8 == 0 && CP >= CINK, "LDS cin pad");
    static_assert((CP / 8) % 2 == 1, "odd chunk stride for bank spread");
    __shared__ __align__(16) unsigned short tile[NSLOT * CP];
    const int tid = threadIdx.x;
    const int bx = blockIdx.x, by = blockIdx.y, z = blockIdx.z;
    const long o0 = off0base + (long)z * zs0;
    const long o1 = off1base + (long)z * zs1;
    const int outW = inW / S, outH = inH / S;
    const int gx0 = bx * OX * S - 1;
    const int gy0 = by * OY * S - 1;

#pragma unroll 1
    for (int s = tid; s < NSLOT; s += 256) {
        const int sy = s / XT;
        const int lx = s - sy * XT;
        const int gy = gy0 + sy;
        const int gx = gx0 + lx;
        const bool ok = ((unsigned)gy < (unsigned)inH) && ((unsigned)gx < (unsigned)inW);
        const long pix = (long)gy * inW + gx;
#pragma unroll
        for (int h = 0; h < CINK / 8; ++h) {
            bf16x8 v;
#pragma unroll
            for (int e = 0; e < 8; ++e) {
                const int c = h * 8 + e;
                unsigned short raw = 0;
                if (c < CIN && ok) {
                    const long ofs = (c < split)
                        ? o0 + (long)c * inH * inW + pix
                        : o1 + (long)(c - split) * inH * inW + pix;
                    const void* src = (c < split) ? vin0 : vin1;
                    if constexpr (INBF)
                        raw = ((const unsigned short*)src)[ofs];
                    else
                        raw = f2bf(((const float*)src)[ofs]);
                }
                v[e] = (short)raw;
            }
            *(bf16x8*)(tile + s * CP + h * 8) = v;
        }
    }
    __syncthreads();

    const int wv = tid >> 6;
    const int l = tid & 63;
    const int ln = l & 15;
    const int lk = l >> 4;
    const int cg = (wv * NT4) / NSP;
    bf16x8 bfr[9 * KST];
#pragma unroll
    for (int tap = 0; tap < 9; ++tap)
#pragma unroll
        for (int h = 0; h < KST; ++h)
            bfr[tap * KST + h] = *(const bf16x8*)(wB + ((long)(tap * COUT + cg * 16 + ln)) * CINK + h * 32 + lk * 8);
    const float bv = bias[cg * 16 + ln];
#pragma unroll 1
    for (int t = 0; t < NT4; ++t) {
        const int sp = wv * NT4 + t - cg * NSP;
        const int tx = sp % NTX;
        const int ty = sp / NTX;
        f32x4 acc;
        acc[0] = bv; acc[1] = bv; acc[2] = bv; acc[3] = bv;
#pragma unroll
        for (int ky = 0; ky < 3; ++ky) {
#pragma unroll
            for (int kx = 0; kx < 3; ++kx) {
                const int yb = ty * S + ky;
                const int xb = (tx * 16 + ln) * S + kx;
                const unsigned short* ap = tile + (yb * XT + xb) * CP + lk * 8;
#pragma unroll
                for (int h = 0; h < KST; ++h) {
                    bf16x8 a = *(const bf16x8*)(ap + h * 32);
                    acc = __builtin_amdgcn_mfma_f32_16x16x32_bf16(a, bfr[(ky * 3 + kx) * KST + h], acc, 0, 0, 0);
                }
            }
        }
        const int ox = bx * OX + tx * 16 + lk * 4;
        const int oy = by * OY + ty;
        float r[4];
#pragma unroll
        for (int e = 0; e < 4; ++e) r[e] = RELU ? fmaxf(acc[e], 0.f) : acc[e];
        const long oidx = (long)z * outZS + ((long)(cg * 16 + ln) * outH + oy) * outW + ox;
        if constexpr (OUTBF) {
            ushort4 o;
            o.x = f2bf(r[0]); o.y = f2bf(r[1]); o.z = f2bf(r[2]); o.w = f2bf(r[3]);
            *(ushort4*)((unsigned short*)vout + oidx) = o;
        } else {
            float4 o = {r[0], r[1], r[2], r[3]};
            *(float4*)((float*)vout + oidx) = o;
        }
    }
}

// ---------------- fp32 LDS-tiled 3x3 conv (stem only: precision-critical) ----------------
template <int CIN, int CCHUNK, int WCH, int COUT, int STRIDE, int TW, int CO_PER, int MW>
__global__ __launch_bounds__(256, MW) void conv3x3_k(
    const float* __restrict__ in0, const float* __restrict__ in1, int split,
    long inOff0, long inOff1, long zs0, long zs1, int inW, int inH,
    const float* __restrict__ wT, const float* __restrict__ bias,
    float* __restrict__ out, long outZS) {
    constexpr int NCG = COUT / CO_PER;
    constexpr int NPXG = 256 / NCG;
    constexpr int NXG = TW / 4;
    constexpr int TH = NPXG / NXG;
    constexpr int INW = (TW - 1) * STRIDE + 3;
    constexpr int INH = (TH - 1) * STRIDE + 3;
    constexpr int WIN = 3 * STRIDE + 3;
    constexpr int XV = (INW + 6) / 4;
    constexpr int LDSW = XV * 4 + 1;
    constexpr int SLOTS = INH * XV;
    static_assert(NPXG % NXG == 0 && NPXG * NCG == 256, "thread mapping");
    static_assert(CIN % CCHUNK == 0 && CCHUNK % WCH == 0, "chunking");
    static_assert(SLOTS <= 256, "staging slots");
    __shared__ float tile[CCHUNK][INH][LDSW];
    __shared__ __align__(16) float wlds[WCH * 9 * COUT];
    const int tid = threadIdx.x;
    const int cg = tid / NPXG;
    const int pg = tid % NPXG;
    const int xg = pg % NXG;
    const int yy = pg / NXG;
    const int bx = blockIdx.x, by = blockIdx.y, z = blockIdx.z;
    const int outW = inW / STRIDE, outH = inH / STRIDE;
    const long off0 = inOff0 + (long)z * zs0;
    const long off1 = inOff1 + (long)z * zs1;
    float* outp = out + (long)z * outZS;
    const bool sact = tid < SLOTS;
    const int sr = tid / XV;
    const int sx = tid - sr * XV;
    const int gxs = bx * TW * STRIDE - 4 + sx * 4;
    const int gy0 = by * TH * STRIDE - 1;

    float acc[4][CO_PER];
    {
        float bv[CO_PER];
#pragma unroll
        for (int jj = 0; jj < CO_PER; jj += 4) {
            float4 b4 = *(const float4*)(bias + cg * CO_PER + jj);
            bv[jj] = b4.x; bv[jj + 1] = b4.y; bv[jj + 2] = b4.z; bv[jj + 3] = b4.w;
        }
#pragma unroll
        for (int p = 0; p < 4; ++p)
#pragma unroll
            for (int j = 0; j < CO_PER; ++j) acc[p][j] = bv[j];
    }

    for (int ch = 0; ch < CIN; ch += CCHUNK) {
        if (sact) {
            const int gy = gy0 + sr;
            const bool yok = (unsigned)gy < (unsigned)inH;
            const bool xfull = (gxs >= 0) && (gxs + 3 < inW);
#pragma unroll
            for (int c = 0; c < CCHUNK; ++c) {
                const int gc = ch + c;
                const float* row = (gc < split)
                    ? in0 + off0 + ((long)gc * inH + gy) * inW
                    : in1 + off1 + ((long)(gc - split) * inH + gy) * inW;
                float4 v = {0.f, 0.f, 0.f, 0.f};
                if (yok) {
                    if (xfull) {
                        v = *(const float4*)(row + gxs);
                    } else {
                        float t[4];
#pragma unroll
                        for (int k = 0; k < 4; ++k) {
                            int gx = gxs + k;
                            t[k] = ((unsigned)gx < (unsigned)inW) ? row[gx] : 0.f;
                        }
                        v = {t[0], t[1], t[2], t[3]};
                    }
                }
                float* dst = &tile[c][sr][sx * 4];
                dst[0] = v.x; dst[1] = v.y; dst[2] = v.z; dst[3] = v.w;
            }
        }
#pragma unroll 1
        for (int wc = 0; wc < CCHUNK; wc += WCH) {
            {
                const float4* wsrc = (const float4*)(wT + (long)(ch + wc) * 9 * COUT);
                float4* wdst = (float4*)wlds;
                constexpr int CNT = WCH * 9 * COUT / 4;
                for (int i = tid; i < CNT; i += 256) wdst[i] = wsrc[i];
            }
            __syncthreads();
#pragma unroll 1
            for (int c = 0; c < WCH; ++c) {
#pragma unroll
                for (int ky = 0; ky < 3; ++ky) {
                    const int ty = yy * STRIDE + ky;
                    const int tx0 = xg * 4 * STRIDE + 3;
                    float xw[WIN];
#pragma unroll
                    for (int i = 0; i < WIN; ++i) xw[i] = tile[wc + c][ty][tx0 + i];
#pragma unroll
                    for (int dx = 0; dx < 3; ++dx) {
                        const float* wp = wlds + ((c * 3 + ky) * 3 + dx) * COUT + cg * CO_PER;
                        float wv[CO_PER];
#pragma unroll
                        for (int jj = 0; jj < CO_PER; jj += 4) {
                            float4 w4 = *(const float4*)(wp + jj);
                            wv[jj] = w4.x; wv[jj + 1] = w4.y; wv[jj + 2] = w4.z; wv[jj + 3] = w4.w;
                        }
#pragma unroll
                        for (int p = 0; p < 4; ++p) {
                            float xv = xw[p * STRIDE + dx];
#pragma unroll
                            for (int j = 0; j < CO_PER; ++j) acc[p][j] = fmaf(xv, wv[j], acc[p][j]);
                        }
                    }
                }
            }
            __syncthreads();
        }
    }

    const int ox0 = bx * TW + xg * 4;
    const int oy = by * TH + yy;
#pragma unroll
    for (int j = 0; j < CO_PER; ++j) {
        int co = cg * CO_PER + j;
        float4 o;
        o.x = fmaxf(acc[0][j], 0.f);
        o.y = fmaxf(acc[1][j], 0.f);
        o.z = fmaxf(acc[2][j], 0.f);
        o.w = fmaxf(acc[3][j], 0.f);
        *(float4*)(outp + ((long)co * outH + oy) * outW + ox0) = o;
    }
}

// ---------------- spatial mean over 96x96 plane, z-batched ----------------
__global__ __launch_bounds__(256) void pool_k(const float* __restrict__ enc3base,
                                              long zstride,
                                              float* __restrict__ meanout) {
    int z = blockIdx.x >> 6;
    int c = blockIdx.x & 63;
    const float* p = enc3base + (long)z * zstride + (long)c * 9216;
    float s = 0.f;
    for (int i = threadIdx.x; i < 9216; i += 256) s += p[i];
    __shared__ float red[256];
    red[threadIdx.x] = s;
    __syncthreads();
    for (int o = 128; o > 0; o >>= 1) {
        if (threadIdx.x < o) red[threadIdx.x] += red[threadIdx.x + o];
        __syncthreads();
    }
    if (threadIdx.x == 0) meanout[z * 64 + c] = red[0] * (1.f / 9216.f);
}

// ---------------- task embedding + te-derived constants ----------------
__global__ __launch_bounds__(256) void prep_te_k(
    const float* __restrict__ means, const float* __restrict__ lw,
    const float* __restrict__ lb, const float* __restrict__ tauw,
    const float* __restrict__ taub, const float* __restrict__ w1,
    const float* __restrict__ b1,
    float* __restrict__ tauc, float* __restrict__ wsum,
    float* __restrict__ bias2) {
    __shared__ float tes[64];
    int t = threadIdx.x;
    if (t < 64) {
        float s = 0.f;
        for (int d = 0; d < 4; ++d)
            for (int c = 0; c < 64; ++c) s += means[d * 64 + c] * lw[t * 64 + c];
        tes[t] = lb[t] + 0.25f * s;
    }
    __syncthreads();
    if (t < 32) {
        float s = taub[t];
        for (int e = 0; e < 64; ++e) s += tauw[t * 96 + 32 + e] * tes[e];
        tauc[t] = s;
    }
    for (int i = t; i < 288; i += 256) {
        int co = i % 32;
        int k = i / 32;
        float s = 0.f;
        for (int e = 0; e < 64; ++e) s += w1[((co * 96) + 32 + e) * 9 + k] * tes[e];
        wsum[i] = s;
    }
    __syncthreads();
    if (t < 32) {
        float s = b1[t];
        for (int k = 0; k < 9; ++k) s += wsum[k * 32 + t];
        bias2[t] = s;  // b1 + full 9-tap te sum (border fixed in fused step)
    }
}

// ---------------- FUSED NCA step: mfma 3x3 + border-corr/relu + 1x1s + gate ----------------
// R22-proven structure. LAST=true additionally fuses the decode: s_new is
// round-tripped through ss (barrier-protected) and the 11-channel 1x1 decode
// is written straight to d_out (skips step-8 s_new write + dec read/launch).
template <bool LAST>
__global__ __launch_bounds__(256, 2) void nca_step_fused_k(
    const float* __restrict__ sold, float* __restrict__ snew,
    const unsigned short* __restrict__ wBE,  // [9][32][32] bf16
    const float* __restrict__ bias2,
    const float* __restrict__ wsum,
    const float* __restrict__ w2T, const float* __restrict__ b2,
    const float* __restrict__ tauT, const float* __restrict__ tauc,
    const float* __restrict__ decT, const float* __restrict__ db,
    float* __restrict__ dout) {
    // XT=34, YT=6, NSLOT=204, CP=40
    __shared__ __align__(16) unsigned short tile[204 * 40];  // 16,320 B; h1s[32][136] after conv
    __shared__ __align__(16) float ss[32][132];              // 16,896 B (fp32 centers)
    __shared__ __align__(16) float sw2[1024], stu[1024];     //  8,192 B
    __shared__ float sb2[32], stc[32];
    __shared__ float sdec[384], sdb[12];
    const int tid = threadIdx.x;
    const int bx = blockIdx.x, by = blockIdx.y;
    const int gx0 = bx * 32 - 1;
    const int gy0 = by * 4 - 1;

    for (int i = tid; i < 1024; i += 256) {
        sw2[i] = w2T[i];
        stu[i] = tauT[i];
    }
    if (tid < 32) {
        sb2[tid] = b2[tid];
        stc[tid] = tauc[tid];
    }
    if constexpr (LAST) {
        for (int i = tid; i < 384; i += 256) sdec[i] = decT[i];
        if (tid < 11) sdb[tid] = db[tid];
    }
    // ---- phase 1: stage tile (bf16) + centers (fp32) ----
    if (tid < 204) {
        const int sy = tid / 34;
        const int lx = tid - sy * 34;
        const int gy = gy0 + sy;
        const int gx = gx0 + lx;
        const bool ok = ((unsigned)gy < 384u) && ((unsigned)gx < 384u);
        const long pix = (long)gy * 384 + gx;
        const bool ctr = (sy >= 1) && (sy <= 4) && (lx >= 1) && (lx <= 32);
        const int pxl = (sy - 1) * 32 + (lx - 1);
#pragma unroll
        for (int h = 0; h < 4; ++h) {
            bf16x8 v;
#pragma unroll
            for (int e = 0; e < 8; ++e) {
                const int c = h * 8 + e;
                float f = ok ? sold[(long)c * HW + pix] : 0.f;
                v[e] = (short)f2bf(f);
                if (ctr) ss[c][pxl] = f;
            }
            *(bf16x8*)(tile + tid * 40 + h * 8) = v;
        }
    }
    __syncthreads();

    // ---- phase 2: mfma conv, 16 tasks (4/wave), results in registers ----
    const int wv = tid >> 6;
    const int l = tid & 63;
    const int ln = l & 15;
    const int lk = l >> 4;
    const int cg = wv >> 1;
    const int co = cg * 16 + ln;
    bf16x8 bfr[9];
#pragma unroll
    for (int tap = 0; tap < 9; ++tap)
        bfr[tap] = *(const bf16x8*)(wBE + ((long)(tap * 32 + co)) * 32 + lk * 8);
    const float bv = bias2[co];
    f32x4 accs[4];
#pragma unroll
    for (int t = 0; t < 4; ++t) {
        const int sp = (wv & 1) * 4 + t;
        const int tx = sp & 1;
        const int ty = sp >> 1;
        f32x4 acc;
        acc[0] = bv; acc[1] = bv; acc[2] = bv; acc[3] = bv;
#pragma unroll
        for (int ky = 0; ky < 3; ++ky) {
#pragma unroll
            for (int kx = 0; kx < 3; ++kx) {
                const unsigned short* ap = tile + ((ty + ky) * 34 + tx * 16 + ln + kx) * 40 + lk * 8;
                bf16x8 a = *(const bf16x8*)ap;
                acc = __builtin_amdgcn_mfma_f32_16x16x32_bf16(a, bfr[ky * 3 + kx], acc, 0, 0, 0);
            }
        }
        accs[t] = acc;
    }
    __syncthreads();  // all tile reads done -> safe to overwrite with h

    // ---- phase 3: border-corr + relu + bf16 h into tile region ----
    unsigned short (*h1s)[136] = (unsigned short(*)[136])tile;
#pragma unroll
    for (int t = 0; t < 4; ++t) {
        const int sp = (wv & 1) * 4 + t;
        const int tx = sp & 1;
        const int ty = sp >> 1;
        const int gy = by * 4 + ty;
        const int gxb = bx * 32 + tx * 16 + lk * 4;
        float hv[4] = {accs[t][0], accs[t][1], accs[t][2], accs[t][3]};
        const bool ytop = (gy == 0), ybot = (gy == 383);
#pragma unroll
        for (int r = 0; r < 4; ++r) {
            const int gx = gxb + r;
            const bool xl = (gx == 0), xr = (gx == 383);
            if (xl | xr | ytop | ybot) {
                float h = hv[r];
#pragma unroll
                for (int ky = 0; ky < 3; ++ky)
#pragma unroll
                    for (int kx = 0; kx < 3; ++kx) {
                        bool inval = (ky == 0 && ytop) || (ky == 2 && ybot) ||
                                     (kx == 0 && xl) || (kx == 2 && xr);
                        if (inval) h -= wsum[(ky * 3 + kx) * 32 + co];
                    }
                hv[r] = h;
            }
        }
        ushort4 ho;
        ho.x = f2bf(fmaxf(hv[0], 0.f));
        ho.y = f2bf(fmaxf(hv[1], 0.f));
        ho.z = f2bf(fmaxf(hv[2], 0.f));
        ho.w = f2bf(fmaxf(hv[3], 0.f));
        *(ushort4*)(&h1s[co][ty * 32 + tx * 16 + lk * 4]) = ho;
    }
    __syncthreads();

    // ---- phase 4: fused 1x1s + gate (proven shape) ----
    const int cg2 = tid >> 5;  // 8 groups x 4 couts
    const int pg = tid & 31;   // 32 x 4 px
    const int p0 = pg * 4;
    float accd[4][4], acct[4][4];
    {
        float dv[4], tv[4];
#pragma unroll
        for (int j = 0; j < 4; ++j) {
            dv[j] = sb2[cg2 * 4 + j];
            tv[j] = stc[cg2 * 4 + j];
        }
#pragma unroll
        for (int p = 0; p < 4; ++p)
#pragma unroll
            for (int j = 0; j < 4; ++j) { accd[p][j] = dv[j]; acct[p][j] = tv[j]; }
    }
#pragma unroll 2
    for (int ci = 0; ci < 32; ++ci) {
        float hv[4], sv[4];
#pragma unroll
        for (int p = 0; p < 4; ++p) {
            hv[p] = bf2f(h1s[ci][p0 + p]);
            sv[p] = ss[ci][p0 + p];
        }
        float4 wd4 = *(const float4*)(sw2 + ci * 32 + cg2 * 4);
        float4 wt4 = *(const float4*)(stu + ci * 32 + cg2 * 4);
        float wdv[4] = {wd4.x, wd4.y, wd4.z, wd4.w};
        float wtv[4] = {wt4.x, wt4.y, wt4.z, wt4.w};
#pragma unroll
        for (int p = 0; p < 4; ++p) {
#pragma unroll
            for (int j = 0; j < 4; ++j) {
                accd[p][j] = fmaf(hv[p], wdv[j], accd[p][j]);
                acct[p][j] = fmaf(sv[p], wtv[j], acct[p][j]);
            }
        }
    }
    float ov4[4][4];
#pragma unroll
    for (int j = 0; j < 4; ++j) {
#pragma unroll
        for (int p = 0; p < 4; ++p) {
            float sown = ss[cg2 * 4 + j][p0 + p];
            float beta = 1.f / (1.f + __expf(-acct[p][j]));
            ov4[j][p] = beta * sown + (1.f - beta) * accd[p][j];
        }
    }
    if constexpr (!LAST) {
        const int yl = p0 >> 5;
        const int xl2 = p0 & 31;
        const long obase = ((long)(by * 4 + yl)) * 384 + bx * 32 + xl2;
#pragma unroll
        for (int j = 0; j < 4; ++j) {
            float4 o = {ov4[j][0], ov4[j][1], ov4[j][2], ov4[j][3]};
            *(float4*)(snew + (long)(cg2 * 4 + j) * HW + obase) = o;
        }
    } else {
        __syncthreads();  // all ci-loop ss reads complete
#pragma unroll
        for (int j = 0; j < 4; ++j)
#pragma unroll
            for (int p = 0; p < 4; ++p)
                ss[cg2 * 4 + j][p0 + p] = ov4[j][p];
        __syncthreads();
        // decode from ss -> d_out
        const int q = tid & 127;
        const int half = tid >> 7;
        const int nco = half ? 5 : 6;
        float acc[6];
#pragma unroll
        for (int j = 0; j < 6; ++j) acc[j] = (j < nco) ? sdb[half * 6 + j] : 0.f;
#pragma unroll 4
        for (int ci = 0; ci < 32; ++ci) {
            float sv = ss[ci][q];
            const float* wp = sdec + ci * 12 + half * 6;
#pragma unroll
            for (int j = 0; j < 6; ++j) acc[j] = fmaf(sv, wp[j], acc[j]);
        }
        const int yq = q >> 5;
        const long pxg = ((long)(by * 4 + yq)) * 384 + bx * 32 + (q & 31);
#pragma unroll
        for (int j = 0; j < 6; ++j) {
            if (j < nco) dout[(long)(half * 6 + j) * HW + pxg] = acc[j];
        }
    }
}

extern "C" void kernel_launch(void* const* d_in, const int* in_sizes, int n_in,
                              void* d_out, int out_size, void* d_ws, size_t ws_size,
                              hipStream_t stream) {
    float* out = (float*)d_out;
    const float* demo_in = (const float*)d_in[0];
    const float* demo_out = (const float*)d_in[1];
    const float* test_in = (const float*)d_in[2];
    const float* enc_w1 = (const float*)d_in[3];
    const float* enc_b1 = (const float*)d_in[4];
    const float* enc_w2 = (const float*)d_in[5];
    const float* enc_b2 = (const float*)d_in[6];
    const float* enc_w3 = (const float*)d_in[7];
    const float* enc_b3 = (const float*)d_in[8];
    const float* enc_lw = (const float*)d_in[9];
    const float* enc_lb = (const float*)d_in[10];
    const float* stem_w = (const float*)d_in[11];
    const float* stem_b = (const float*)d_in[12];
    const float* upd_w1 = (const float*)d_in[13];
    const float* upd_b1 = (const float*)d_in[14];
    const float* upd_w2 = (const float*)d_in[15];
    const float* upd_b2 = (const float*)d_in[16];
    const float* tau_w = (const float*)d_in[17];
    const float* tau_b = (const float*)d_in[18];
    const float* dec_w = (const float*)d_in[19];
    const float* dec_b = (const float*)d_in[20];

    // ---- workspace layout (floats) ----
    float* Wb = (float*)d_ws;
    float* wT_D = Wb + 0;        // 3744 (stem fp32)
    float* w2T  = Wb + 3744;     // 1024
    float* tauT = Wb + 4768;     // 1024
    float* decT = Wb + 5792;     // 384
    float* tauc = Wb + 6176;     // 32
    float* wsum = Wb + 6208;     // 288
    float* means = Wb + 6496;    // 256
    float* bias2 = Wb + 6752;    // 32
    unsigned short* wB1 = (unsigned short*)(Wb + 6784);   // 9*32*32 bf16 (4608 f)
    unsigned short* wB2 = (unsigned short*)(Wb + 11392);  // 9*64*32 (9216 f)
    unsigned short* wB3 = (unsigned short*)(Wb + 20608);  // 9*64*64 (18432 f)
    unsigned short* wBE = (unsigned short*)(Wb + 39040);  // 9*32*32 (4608 f)
    float* big = Wb + 45056;

    const long E1 = 4718592;  // 32*HW elements
    const long E2 = 2359296;  // 64*192*192 elements
    const long E3 = 589824;   // 64*96*96 elements
    // Encoder intermediates (bf16) overlap the state region: encoder finishes
    // before the stem writes sA. Per-NZ footprint = NZ*(E1+E2)/2 + NZ*E3 floats.
    size_t wsf = ws_size / 4;
    int NZ = (wsf >= (size_t)(45056 + 4 * 4128768L)) ? 4 : 2;
    unsigned short* enc1b = (unsigned short*)big;             // NZ*E1 ushorts
    unsigned short* enc2b = enc1b + (long)NZ * E1;            // NZ*E2 ushorts
    float* enc3f = (float*)(enc2b + (long)NZ * E2);           // NZ*E3 floats

    // ---- fp32 weight transposes (stem + 1x1s + dec) ----
    TJobs J;
    {
        const float* srcs[5] = {stem_w, upd_w2, tau_w, dec_w, dec_w};
        float* dsts[5] = {wT_D, w2T, tauT, decT, decT};
        int couts[5] = {32, 32, 32, 11, 0};
        int cintots[5] = {13, 32, 96, 32, 32};
        int ks[5] = {9, 1, 1, 1, 1};
        int cinsels[5] = {13, 32, 32, 32, 0};
        int coutps[5] = {32, 32, 32, 12, 12};
        int acc0 = 0;
        for (int j = 0; j < 5; ++j) {
            J.src[j] = srcs[j]; J.dst[j] = dsts[j];
            J.cout[j] = couts[j]; J.cintot[j] = cintots[j];
            J.k[j] = ks[j]; J.coutp[j] = coutps[j];
            J.start[j] = acc0;
            acc0 += cinsels[j] * ks[j] * coutps[j];
        }
        J.start[5] = acc0;
        transpose_all_k<<<(acc0 + 255) / 256, 256, 0, stream>>>(J);
    }
    // ---- bf16 MFMA weights (encoder convs + nca 3x3 state part) ----
    WJobs W;
    {
        const float* srcs[4] = {enc_w1, enc_w2, enc_w3, upd_w1};
        unsigned short* dsts[4] = {wB1, wB2, wB3, wBE};
        int couts[4] = {32, 64, 64, 32};
        int cins[4] = {26, 32, 64, 32};
        int cintots[4] = {26, 32, 64, 96};
        int cinps[4] = {32, 32, 64, 32};
        int acc0 = 0;
        for (int j = 0; j < 4; ++j) {
            W.src[j] = srcs[j]; W.dst[j] = dsts[j];
            W.cout[j] = couts[j]; W.cin[j] = cins[j];
            W.cintot[j] = cintots[j]; W.cinp[j] = cinps[j];
            W.start[j] = acc0;
            acc0 += 9 * couts[j] * cinps[j];
        }
        W.start[4] = acc0;
        transpose_wbf_k<<<(acc0 + 255) / 256, 256, 0, stream>>>(W);
    }

    // ---- encoder (bf16 MFMA, bf16 intermediates), NZ demos per launch ----
    for (int d0 = 0; d0 < 4; d0 += NZ) {
        mfma_conv_k<26, 40, 32, 1, 64, 4, 5, true, false, true>
            <<<dim3(6, 96, NZ), 256, 0, stream>>>(
            demo_in, demo_out, 13, (long)d0 * 13 * HW, (long)d0 * 13 * HW,
            13L * HW, 13L * HW, 384, 384, wB1, enc_b1,
            enc1b + (long)d0 * E1, E1);
        mfma_conv_k<32, 40, 64, 2, 32, 2, 5, true, true, true>
            <<<dim3(6, 96, NZ), 256, 0, stream>>>(
            enc1b + (long)d0 * E1, enc1b + (long)d0 * E1, 32, 0, 0, E1, E1,
            384, 384, wB2, enc_b2, enc2b + (long)d0 * E2, E2);
        mfma_conv_k<64, 72, 64, 2, 16, 2, 5, true, true, false>
            <<<dim3(6, 48, NZ), 256, 0, stream>>>(
            enc2b + (long)d0 * E2, enc2b + (long)d0 * E2, 64, 0, 0, E2, E2,
            192, 192, wB3, enc_b3, enc3f + (long)d0 * E3, E3);
        pool_k<<<64 * NZ, 256, 0, stream>>>(enc3f + (long)d0 * E3, E3,
                                            means + d0 * 64);
    }
    prep_te_k<<<1, 256, 0, stream>>>(means, enc_lw, enc_lb, tau_w, tau_b, upd_w1,
                                     upd_b1, tauc, wsum, bias2);

    // ---- stem (fp32 exact) -> sA (overlaps dead encoder buffers) ----
    float* sA = big;
    float* sX = big + E1;
    conv3x3_k<13, 13, 13, 32, 1, 32, 8, 5><<<dim3(12, 48, 1), 256, 0, stream>>>(
        test_in, test_in, 13, 0, 0, 0, 0, 384, 384, wT_D, stem_b, sA, 0);

    // ---- 8 fused NCA steps (n_steps==8 per setup_inputs); last fuses decode ----
    float* a = sA;
    float* b = sX;
    for (int s = 0; s < 7; ++s) {
        nca_step_fused_k<false><<<dim3(12, 96), 256, 0, stream>>>(
            a, b, wBE, bias2, wsum, w2T, upd_b2, tauT, tauc, decT, dec_b, out);
        float* t = a; a = b; b = t;
    }
    nca_step_fused_k<true><<<dim3(12, 96), 256, 0, stream>>>(
        a, b, wBE, bias2, wsum, w2T, upd_b2, tauT, tauc, decT, dec_b, out);
}